// Round 8
// baseline (433.107 us; speedup 1.0000x reference)
//
#include <hip/hip_runtime.h>
#include <hip/hip_bf16.h>

#define B_ 4
#define L_ 2052
#define C_ 1024
#define H_ 16
#define D_ 64
#define NREG_ 4
#define M_ (B_*L_)     // 8208
#define LP_ 2056       // padded L stride for Vt (16B-aligned rows)
#define QSC 0.18033688f  // 0.125 * log2(e), applied in fp32 inside attn

typedef short bf16x8 __attribute__((ext_vector_type(8)));
typedef float f32x4 __attribute__((ext_vector_type(4)));
typedef __hip_bfloat16 bf16;

#define MFMA(a,b,c) __builtin_amdgcn_mfma_f32_16x16x32_bf16(a,b,c,0,0,0)

__device__ inline float b2f(bf16 v){ return __bfloat162float(v); }
__device__ inline bf16  f2b(float v){ return __float2bfloat16(v); }
__device__ inline bf16x8 as8(int4 v){ union{int4 i; bf16x8 b;} u; u.i=v; return u.b; }

// async global->LDS, 16B per lane; LDS dest = wave-uniform base + lane*16
__device__ inline void gl_lds16(const void* g, void* l){
    __builtin_amdgcn_global_load_lds(
        (const __attribute__((address_space(1))) void*)g,
        (__attribute__((address_space(3))) void*)l,
        16, 0, 0);
}

// bijective XCD-aware remap (m204): contiguous chunk of ids per XCD
__device__ inline int xcd_swizzle(int orig, int nwg){
    int xcd = orig & 7, idx = orig >> 3;
    int q8 = nwg >> 3, r8 = nwg & 7;
    return (xcd < r8 ? xcd*(q8+1) : r8*(q8+1) + (xcd-r8)*q8) + idx;
}

// ---------------- x -> bf16 hi/lo split ----------------
__global__ __launch_bounds__(256)
void cvt_split(const float* __restrict__ in, bf16* __restrict__ hi,
               bf16* __restrict__ lo, int n)
{
    int i = (blockIdx.x*256 + threadIdx.x)*4;
    if (i >= n) return;
    float4 v = *(const float4*)(in + i);
    int2 hraw, lraw;
    bf16* hp = (bf16*)&hraw;
    bf16* lp = (bf16*)&lraw;
    float vv[4] = {v.x, v.y, v.z, v.w};
    #pragma unroll
    for (int j=0;j<4;++j){
        bf16 h = f2b(vv[j]);
        hp[j] = h;
        lp[j] = f2b(vv[j] - b2f(h));
    }
    *(int2*)(hi + i) = hraw;
    *(int2*)(lo + i) = lraw;
}

// ---------------- fp32 [R][Cc] -> bf16 transposed [Cc][R] ----------------
__global__ __launch_bounds__(256)
void transpose_cvt(const float* __restrict__ in, bf16* __restrict__ out,
                   int R, int Cc)
{
    __shared__ bf16 t[32][33];
    int bx = blockIdx.x * 32;
    int by = blockIdx.y * 32;
    int tx = threadIdx.x;
    int ty = threadIdx.y;
    #pragma unroll
    for (int i=0;i<4;++i){
        int r = by + ty + i*8;
        int c = bx + tx;
        t[ty+i*8][tx] = f2b(in[(size_t)r*Cc + c]);
    }
    __syncthreads();
    #pragma unroll
    for (int i=0;i<4;++i){
        int r = bx + ty + i*8;
        int c = by + tx;
        out[(size_t)r*R + c] = t[tx][ty+i*8];
    }
}

// ---- GEMM, block tile 128x256, wave tile 64x128 (mi4 x ni8) ----
// Round-2 structure (best measured) + bijective XCD swizzle (T1): 1D grid,
// chunked id->XCD mapping so blocks sharing the A-panel hit the same L2.
// single-buffer global_load_lds width-16, linear LDS (stride 32 = BK),
// XOR slot swizzle p = q ^ ((row>>2)&3) on BOTH global source and ds_read.
// A[M][K] (+optional lo) x Bt[N][K] -> C[M][N] + bias. N%256==0, K%32==0.
template<typename OutT, bool SPLIT>
__global__ __launch_bounds__(256,2)
void gemm_wide(const bf16* __restrict__ A, const bf16* __restrict__ Alo,
               const bf16* __restrict__ Bt, const float* __restrict__ bias,
               OutT* __restrict__ C, int M, int N, int K, int NBX)
{
    __shared__ bf16 As[128*32];
    __shared__ bf16 Als[SPLIT ? 128*32 : 8];
    __shared__ bf16 Bs[256*32];

    int tid  = threadIdx.x;
    int lane = tid & 63, wave = tid >> 6;
    int wm = (wave>>1)*64, wn = (wave&1)*128;
    int wg = xcd_swizzle(blockIdx.x, gridDim.x);
    int bm = (wg / NBX)*128, bn = (wg % NBX)*256;
    int lrow = lane & 15;
    int quad = lane >> 4;
    int sw8  = (quad ^ ((lrow>>2)&3)) * 8;   // swizzled element offset for frag reads

    f32x4 acc[4][8] = {};

    for (int k0 = 0; k0 < K; k0 += 32) {
        // ---- stage A (+Alo): 8KB each, 2 calls/wave ----
        #pragma unroll
        for (int it=0; it<2; ++it) {
            int o  = (wave*2+it)*1024 + lane*16;  // LDS byte offset this lane lands at
            int r  = o >> 6;                      // row 0..127
            int p  = (o >> 4) & 3;                // physical 16B slot in row
            int ls = p ^ ((r>>2)&3);              // logical slot to fetch
            int ga = bm + r; if (ga >= M) ga = M-1;
            gl_lds16(A + (size_t)ga*K + k0 + ls*8, &As[(wave*2+it)*512]);
            if constexpr (SPLIT)
                gl_lds16(Alo + (size_t)ga*K + k0 + ls*8, &Als[(wave*2+it)*512]);
        }
        // ---- stage B: 16KB, 4 calls/wave ----
        #pragma unroll
        for (int it=0; it<4; ++it) {
            int o  = (wave*4+it)*1024 + lane*16;
            int r  = o >> 6;                      // row 0..255
            int p  = (o >> 4) & 3;
            int ls = p ^ ((r>>2)&3);
            gl_lds16(Bt + (size_t)(bn + r)*K + k0 + ls*8, &Bs[(wave*4+it)*512]);
        }
        __syncthreads();   // compiler drains vmcnt(0) here: staging visible

        bf16x8 b[8];
        #pragma unroll
        for (int i=0;i<8;++i)
            b[i] = *(const bf16x8*)(&Bs[(wn+i*16+lrow)*32 + sw8]);
        #pragma unroll
        for (int mi=0;mi<4;++mi){
            bf16x8 a = *(const bf16x8*)(&As[(wm+mi*16+lrow)*32 + sw8]);
            #pragma unroll
            for (int ni=0;ni<8;++ni)
                acc[mi][ni] = MFMA(a, b[ni], acc[mi][ni]);
            if constexpr (SPLIT) {
                bf16x8 al = *(const bf16x8*)(&Als[(wm+mi*16+lrow)*32 + sw8]);
                #pragma unroll
                for (int ni=0;ni<8;++ni)
                    acc[mi][ni] = MFMA(al, b[ni], acc[mi][ni]);
            }
        }
        __syncthreads();   // reads done before next iteration's staging overwrites
    }

    #pragma unroll
    for (int ni=0;ni<8;++ni){
        int col = bn + wn + ni*16 + lrow;
        float bv = bias[col];
        #pragma unroll
        for (int mi=0;mi<4;++mi){
            int rowb = bm + wm + mi*16 + quad*4;
            #pragma unroll
            for (int r=0;r<4;++r){
                int row = rowb + r;
                if (row < M) {
                    float v = acc[mi][ni][r] + bv;
                    if constexpr (sizeof(OutT)==4) C[(size_t)row*N + col] = v;
                    else                           C[(size_t)row*N + col] = f2b(v);
                }
            }
        }
    }
}

// ---------------- RoPE in-place on q,k (pure rotation) ----------------
__global__ __launch_bounds__(256)
void rope_kernel(bf16* __restrict__ qkv, const float* __restrict__ rope)
{
    int idx = blockIdx.x*256 + threadIdx.x;
    int d = idx & 31;
    int h = (idx >> 5) & 15;
    int m = idx >> 9;
    if (m >= M_) return;
    int l = m % L_;
    if (l < NREG_) return;
    const float* cp = rope + (size_t)(l - NREG_)*D_;
    const float* sp = rope + (size_t)(L_ - NREG_)*D_ + (size_t)(l - NREG_)*D_;
    float c0 = cp[d], c1 = cp[d+32], s0 = sp[d], s1 = sp[d+32];
    size_t base = (size_t)m*3072 + h*64;
    {
        float a = b2f(qkv[base + d]), b = b2f(qkv[base + d + 32]);
        qkv[base + d]      = f2b(a*c0 - b*s0);
        qkv[base + d + 32] = f2b(b*c1 + a*s1);
    }
    {
        size_t kb = base + 1024;
        float a = b2f(qkv[kb + d]), b = b2f(qkv[kb + d + 32]);
        qkv[kb + d]      = f2b(a*c0 - b*s0);
        qkv[kb + d + 32] = f2b(b*c1 + a*s1);
    }
}

// ---------------- V -> Vt [B*H][D][LP_] (zero-padded cols) ----------------
__global__ __launch_bounds__(256)
void transpose_v(const bf16* __restrict__ qkv, bf16* __restrict__ Vt)
{
    __shared__ bf16 t[64*72];
    int bh = blockIdx.y, lt = blockIdx.x;
    int b = bh >> 4, h = bh & 15;
    int tid = threadIdx.x;
    #pragma unroll
    for (int it=0; it<2; ++it){
        int i = tid + it*256;
        int il = i >> 3, c = (i&7)*8;
        int l = lt*64 + il;
        int4 v = {0,0,0,0};
        if (l < L_) v = *(const int4*)(qkv + ((size_t)b*L_ + l)*3072 + 2048 + h*64 + c);
        *(int4*)(&t[il*72 + c]) = v;
    }
    __syncthreads();
    #pragma unroll
    for (int it=0; it<2; ++it){
        int i = tid + it*256;
        int d = i >> 3, ck = (i&7)*8;
        if (lt*64 + ck + 8 <= LP_){
            union { int4 q; bf16 e[8]; } u;
            #pragma unroll
            for (int j=0;j<8;++j) u.e[j] = t[(ck+j)*72 + d];
            *(int4*)(&Vt[((size_t)bh*64 + d)*LP_ + lt*64 + ck]) = u.q;
        }
    }
}

// ---------------- flash attention (round-15: QBLK=256, q_w=64, XCD swizzle) ----------------
// Register-resident P: PV = MFMA(V^T-frag, P-as-B-frag); K slot permutation
// folded into the gl_lds SOURCE address makes each lane's 8 P keys lane-local.
// q_w widened 48->64: per-wave LDS K/V re-read amortized over 1.33x more MFMA
// (the loop is LDS-read-pipe bound). All staging via global_load_lds with
// linear LDS dest + inverse-XOR-swizzled source + XOR-swizzled ds_reads.
// LDS: Q 256x64 (32KB) + K 64x64 (8KB) + V 64x64 (8KB) = 48KB.
__global__ __launch_bounds__(256,2)
void attn_kernel(const bf16* __restrict__ qkv, const bf16* __restrict__ Vt,
                 float* __restrict__ out)
{
    __shared__ bf16 sQ[256*64];
    __shared__ bf16 sK[64*64];    // [key-slot][d], slot rows permuted via source
    __shared__ bf16 sV[64*64];    // [d][key]

    int tid = threadIdx.x, lane = tid & 63, wave = tid >> 6;
    int lrow = lane & 15, quad = lane >> 4;
    int wg = xcd_swizzle(blockIdx.x, gridDim.x);
    int qt = wg % 9, bh = wg / 9;
    int b  = bh >> 4, h = bh & 15;
    size_t rowbase = (size_t)b * L_;
    int q0 = qt * 256;

    int l8   = lane >> 3;         // staging sub-row 0..7
    int p3   = lane & 7;          // physical 16B slot (linear dest)
    int swz0 = (quad     ^ (lrow&7))*8;   // read swizzle, slot s=0
    int swz1 = ((4+quad) ^ (lrow&7))*8;   // read swizzle, slot s=1

    // ---- stage Q: 32KB = 32 gl_lds, 8 per wave ----
    #pragma unroll
    for (int it=0; it<8; ++it){
        int ci  = wave*8 + it;
        int row = ci*8 + l8;                 // 0..255
        int ls  = p3 ^ (row&7);
        int gq  = q0 + row; if (gq >= L_) gq = L_-1;
        gl_lds16(qkv + (rowbase + gq)*3072 + h*64 + ls*8, &sQ[ci*512]);
    }
    __syncthreads();

    bf16x8 qf[4][2];
    #pragma unroll
    for (int qi=0;qi<4;++qi){
        qf[qi][0] = *(const bf16x8*)(&sQ[(wave*64 + qi*16 + lrow)*64 + swz0]);
        qf[qi][1] = *(const bf16x8*)(&sQ[(wave*64 + qi*16 + lrow)*64 + swz1]);
    }

    f32x4 o_[4][4] = {};
    f32x4 lsum[4] = {};

    bf16x8 onesf;
    #pragma unroll
    for (int j=0;j<8;++j) onesf[j] = (short)0x3F80;   // bf16 1.0

    const bf16* kgbase = qkv + rowbase*3072 + 1024 + h*64;
    const bf16* vgbase = Vt + (size_t)bh*64*LP_;

    for (int kt = 0; kt <= 32; ++kt) {
        // ---- stage K (8KB) + V (8KB): 2+2 gl_lds per wave ----
        #pragma unroll
        for (int it=0; it<2; ++it){
            int ci  = wave*2 + it;
            int row = ci*8 + l8;                 // slot 0..63
            int ls  = p3 ^ (row&7);
            // slot -> key permutation (lane-local P for PV):
            int key = kt*64 + ((row & 0x23) | ((row & 0x0C) << 1) | ((row & 0x10) >> 2));
            if (key >= L_) key = L_-1;           // tail clamp (masked below)
            gl_lds16(kgbase + (size_t)key*3072 + ls*8, &sK[ci*512]);
        }
        #pragma unroll
        for (int it=0; it<2; ++it){
            int ci  = wave*2 + it;
            int row = ci*8 + l8;                 // d 0..63
            int ls  = p3 ^ (row&7);
            int col = kt*64 + ls*8;
            if (col + 8 > LP_) col = 0;          // tail clamp (P=0 there)
            gl_lds16(vgbase + (size_t)row*LP_ + col, &sV[ci*512]);
        }
        __syncthreads();   // vmcnt(0) drained: staged tile visible

        bool full = (kt != 32);
        int4 pb[4][2];     // P as B-fragments: [qi][32-key half], lane-local

        #pragma unroll
        for (int ki=0; ki<4; ++ki){
            bf16x8 kf0 = *(const bf16x8*)(&sK[(ki*16+lrow)*64 + swz0]);
            bf16x8 kf1 = *(const bf16x8*)(&sK[(ki*16+lrow)*64 + swz1]);
            #pragma unroll
            for (int qi=0; qi<4; ++qi){
                f32x4 t = {};
                t = MFMA(kf0, qf[qi][0], t);
                t = MFMA(kf1, qf[qi][1], t);
                float p[4];
                #pragma unroll
                for (int r=0;r<4;++r){
                    float e = __builtin_amdgcn_exp2f(t[r]*QSC);
                    int keyi = (ki>>1)*32 + quad*8 + (ki&1)*4 + r;
                    p[r] = (full || (2048 + keyi) < L_) ? e : 0.f;
                }
                union { int2 d2; __hip_bfloat162 h2[2]; } u;
                u.h2[0] = __float22bfloat162_rn({p[0], p[1]});
                u.h2[1] = __float22bfloat162_rn({p[2], p[3]});
                if ((ki & 1) == 0){ pb[qi][ki>>1].x = u.d2.x; pb[qi][ki>>1].y = u.d2.y; }
                else              { pb[qi][ki>>1].z = u.d2.x; pb[qi][ki>>1].w = u.d2.y; }
            }
        }

        #pragma unroll
        for (int ni=0; ni<4; ++ni){
            bf16x8 vf0 = *(const bf16x8*)(&sV[(ni*16+lrow)*64 + swz0]);
            bf16x8 vf1 = *(const bf16x8*)(&sV[(ni*16+lrow)*64 + swz1]);
            #pragma unroll
            for (int mi=0; mi<4; ++mi){
                f32x4 t = o_[mi][ni];
                t = MFMA(vf0, as8(pb[mi][0]), t);
                t = MFMA(vf1, as8(pb[mi][1]), t);
                o_[mi][ni] = t;
            }
        }
        #pragma unroll
        for (int mi=0; mi<4; ++mi){
            lsum[mi] = MFMA(onesf, as8(pb[mi][0]), lsum[mi]);
            lsum[mi] = MFMA(onesf, as8(pb[mi][1]), lsum[mi]);
        }
        __syncthreads();   // all reads done before next tile's staging overwrites
    }

    // O^T layout: lane holds q = lane&15 (within mi group), d = ni*16 + quad*4 + r
    #pragma unroll
    for (int mi=0; mi<4; ++mi){
        float inv = 1.f / lsum[mi][0];
        int lq = q0 + wave*64 + mi*16 + lrow;
        if (lq < L_){
            size_t base = (rowbase + lq)*1024 + h*64;
            #pragma unroll
            for (int ni=0; ni<4; ++ni){
                f32x4 t = o_[mi][ni];
                float4 w = {t[0]*inv, t[1]*inv, t[2]*inv, t[3]*inv};
                *(float4*)(&out[base + ni*16 + quad*4]) = w;
            }
        }
    }
}

// ---------------- LayerNorm (fp32 in) -> bf16 ----------------
__global__ __launch_bounds__(256)
void ln_kernel(const float* __restrict__ in, const float* __restrict__ gamma,
               const float* __restrict__ beta, bf16* __restrict__ y)
{
    int row = blockIdx.x;
    int tid = threadIdx.x;
    int wave = tid >> 6, lane = tid & 63;
    float4 v4 = *(const float4*)(in + (size_t)row*1024 + tid*4);
    float v[4] = {v4.x, v4.y, v4.z, v4.w};
    float s = 0.f, q = 0.f;
    #pragma unroll
    for (int j=0;j<4;++j){ s += v[j]; q += v[j]*v[j]; }
    #pragma unroll
    for (int o=1;o<64;o<<=1){ s += __shfl_xor(s, o); q += __shfl_xor(q, o); }
    __shared__ float sh[8];
    if (lane == 0){ sh[wave] = s; sh[4+wave] = q; }
    __syncthreads();
    s = sh[0]+sh[1]+sh[2]+sh[3];
    q = sh[4]+sh[5]+sh[6]+sh[7];
    float mu  = s * (1.f/1024.f);
    float var = q * (1.f/1024.f) - mu*mu;
    float rstd = rsqrtf(var + 1e-5f);
    int2 raw;
    bf16* ob = (bf16*)&raw;
    #pragma unroll
    for (int j=0;j<4;++j){
        float g = gamma[tid*4+j], be = beta[tid*4+j];
        ob[j] = f2b((v[j]-mu)*rstd*g + be);
    }
    *(int2*)(y + (size_t)row*1024 + tid*4) = raw;
}

// ---------------- launch ----------------
extern "C" void kernel_launch(void* const* d_in, const int* in_sizes, int n_in,
                              void* d_out, int out_size, void* d_ws, size_t ws_size,
                              hipStream_t stream)
{
    const float* x     = (const float*)d_in[0];
    const float* rope  = (const float*)d_in[1];
    const float* Wqkv  = (const float*)d_in[2];
    const float* bqkv  = (const float*)d_in[3];
    const float* Wproj = (const float*)d_in[4];
    const float* bproj = (const float*)d_in[5];
    const float* lng   = (const float*)d_in[6];
    const float* lnb   = (const float*)d_in[7];
    float* out = (float*)d_out;

    char* ws = (char*)d_ws;
    size_t off = 0;
    auto alloc = [&](size_t bytes)->char* {
        char* p = ws + off;
        off += (bytes + 255) & ~(size_t)255;
        return p;
    };
    bf16* xhi    = (bf16*)alloc((size_t)M_*C_*2);
    bf16* xlo    = (bf16*)alloc((size_t)M_*C_*2);
    bf16* WqkvT  = (bf16*)alloc((size_t)3*C_*C_*2);
    bf16* WprojT = (bf16*)alloc((size_t)C_*C_*2);
    bf16* qkv    = (bf16*)alloc((size_t)M_*3*C_*2);
    bf16* Vt     = (bf16*)alloc((size_t)B_*H_*D_*LP_*2);

    float* attnF = (float*)xhi;        // xhi+xlo region = exactly M*C*4 bytes
    bf16*  y     = qkv;                // qkv dead after attention

    cvt_split<<<M_*C_/1024, 256, 0, stream>>>(x, xhi, xlo, M_*C_);
    transpose_cvt<<<dim3(3*C_/32, C_/32), dim3(32,8), 0, stream>>>(Wqkv, WqkvT, C_, 3*C_);
    transpose_cvt<<<dim3(C_/32, C_/32), dim3(32,8), 0, stream>>>(Wproj, WprojT, C_, C_);
    gemm_wide<bf16, true><<<(3*C_/256)*((M_+127)/128), 256, 0, stream>>>(
        xhi, xlo, WqkvT, bqkv, qkv, M_, 3*C_, C_, 3*C_/256);
    rope_kernel<<<(M_*H_*32)/256, 256, 0, stream>>>(qkv, rope);
    transpose_v<<<dim3((L_+63)/64, B_*H_), 256, 0, stream>>>(qkv, Vt);
    attn_kernel<<<((L_+255)/256)*B_*H_, 256, 0, stream>>>(qkv, Vt, attnF);
    ln_kernel<<<M_, 256, 0, stream>>>(attnF, lng, lnb, y);
    gemm_wide<float, false><<<(C_/256)*((M_+127)/128), 256, 0, stream>>>(
        y, nullptr, WprojT, bproj, out, M_, C_, C_, C_/256);
}

// Round 9
// 416.042 us; speedup vs baseline: 1.0410x; 1.0410x over previous
//
#include <hip/hip_runtime.h>
#include <hip/hip_bf16.h>

#define B_ 4
#define L_ 2052
#define C_ 1024
#define H_ 16
#define D_ 64
#define NREG_ 4
#define M_ (B_*L_)     // 8208
#define LP_ 2056       // padded L stride for Vt (16B-aligned rows)
#define QSC 0.18033688f  // 0.125 * log2(e), applied in fp32 inside attn

typedef short bf16x8 __attribute__((ext_vector_type(8)));
typedef float f32x4 __attribute__((ext_vector_type(4)));
typedef __hip_bfloat16 bf16;

#define MFMA(a,b,c) __builtin_amdgcn_mfma_f32_16x16x32_bf16(a,b,c,0,0,0)

__device__ inline float b2f(bf16 v){ return __bfloat162float(v); }
__device__ inline bf16  f2b(float v){ return __float2bfloat16(v); }
__device__ inline bf16x8 as8(int4 v){ union{int4 i; bf16x8 b;} u; u.i=v; return u.b; }

// async global->LDS, 16B per lane; LDS dest = wave-uniform base + lane*16
__device__ inline void gl_lds16(const void* g, void* l){
    __builtin_amdgcn_global_load_lds(
        (const __attribute__((address_space(1))) void*)g,
        (__attribute__((address_space(3))) void*)l,
        16, 0, 0);
}

// bijective XCD-aware remap (m204): contiguous chunk of ids per XCD
__device__ inline int xcd_swizzle(int orig, int nwg){
    int xcd = orig & 7, idx = orig >> 3;
    int q8 = nwg >> 3, r8 = nwg & 7;
    return (xcd < r8 ? xcd*(q8+1) : r8*(q8+1) + (xcd-r8)*q8) + idx;
}

// ---------------- x -> bf16 hi/lo split ----------------
__global__ __launch_bounds__(256)
void cvt_split(const float* __restrict__ in, bf16* __restrict__ hi,
               bf16* __restrict__ lo, int n)
{
    int i = (blockIdx.x*256 + threadIdx.x)*4;
    if (i >= n) return;
    float4 v = *(const float4*)(in + i);
    int2 hraw, lraw;
    bf16* hp = (bf16*)&hraw;
    bf16* lp = (bf16*)&lraw;
    float vv[4] = {v.x, v.y, v.z, v.w};
    #pragma unroll
    for (int j=0;j<4;++j){
        bf16 h = f2b(vv[j]);
        hp[j] = h;
        lp[j] = f2b(vv[j] - b2f(h));
    }
    *(int2*)(hi + i) = hraw;
    *(int2*)(lo + i) = lraw;
}

// ---------------- fp32 [R][Cc] -> bf16 transposed [Cc][R] ----------------
__global__ __launch_bounds__(256)
void transpose_cvt(const float* __restrict__ in, bf16* __restrict__ out,
                   int R, int Cc)
{
    __shared__ bf16 t[32][33];
    int bx = blockIdx.x * 32;
    int by = blockIdx.y * 32;
    int tx = threadIdx.x;
    int ty = threadIdx.y;
    #pragma unroll
    for (int i=0;i<4;++i){
        int r = by + ty + i*8;
        int c = bx + tx;
        t[ty+i*8][tx] = f2b(in[(size_t)r*Cc + c]);
    }
    __syncthreads();
    #pragma unroll
    for (int i=0;i<4;++i){
        int r = bx + ty + i*8;
        int c = by + tx;
        out[(size_t)r*R + c] = t[tx][ty+i*8];
    }
}

// ---- GEMM, block tile 128x256, wave tile 64x128 (mi4 x ni8) ----
// Round-2 structure + bijective XCD swizzle (T1, VERIFIED round-8: FETCH
// 144.8->69.3 MB, dur 142.4->138.1): 1D grid, chunked id->XCD mapping so
// blocks sharing the A-panel hit the same L2. single-buffer global_load_lds
// width-16, linear LDS (stride 32 = BK), XOR slot swizzle on both sides.
// A[M][K] (+optional lo) x Bt[N][K] -> C[M][N] + bias. N%256==0, K%32==0.
template<typename OutT, bool SPLIT>
__global__ __launch_bounds__(256,2)
void gemm_wide(const bf16* __restrict__ A, const bf16* __restrict__ Alo,
               const bf16* __restrict__ Bt, const float* __restrict__ bias,
               OutT* __restrict__ C, int M, int N, int K, int NBX)
{
    __shared__ bf16 As[128*32];
    __shared__ bf16 Als[SPLIT ? 128*32 : 8];
    __shared__ bf16 Bs[256*32];

    int tid  = threadIdx.x;
    int lane = tid & 63, wave = tid >> 6;
    int wm = (wave>>1)*64, wn = (wave&1)*128;
    int wg = xcd_swizzle(blockIdx.x, gridDim.x);
    int bm = (wg / NBX)*128, bn = (wg % NBX)*256;
    int lrow = lane & 15;
    int quad = lane >> 4;
    int sw8  = (quad ^ ((lrow>>2)&3)) * 8;   // swizzled element offset for frag reads

    f32x4 acc[4][8] = {};

    for (int k0 = 0; k0 < K; k0 += 32) {
        // ---- stage A (+Alo): 8KB each, 2 calls/wave ----
        #pragma unroll
        for (int it=0; it<2; ++it) {
            int o  = (wave*2+it)*1024 + lane*16;  // LDS byte offset this lane lands at
            int r  = o >> 6;                      // row 0..127
            int p  = (o >> 4) & 3;                // physical 16B slot in row
            int ls = p ^ ((r>>2)&3);              // logical slot to fetch
            int ga = bm + r; if (ga >= M) ga = M-1;
            gl_lds16(A + (size_t)ga*K + k0 + ls*8, &As[(wave*2+it)*512]);
            if constexpr (SPLIT)
                gl_lds16(Alo + (size_t)ga*K + k0 + ls*8, &Als[(wave*2+it)*512]);
        }
        // ---- stage B: 16KB, 4 calls/wave ----
        #pragma unroll
        for (int it=0; it<4; ++it) {
            int o  = (wave*4+it)*1024 + lane*16;
            int r  = o >> 6;                      // row 0..255
            int p  = (o >> 4) & 3;
            int ls = p ^ ((r>>2)&3);
            gl_lds16(Bt + (size_t)(bn + r)*K + k0 + ls*8, &Bs[(wave*4+it)*512]);
        }
        __syncthreads();   // compiler drains vmcnt(0) here: staging visible

        bf16x8 b[8];
        #pragma unroll
        for (int i=0;i<8;++i)
            b[i] = *(const bf16x8*)(&Bs[(wn+i*16+lrow)*32 + sw8]);
        #pragma unroll
        for (int mi=0;mi<4;++mi){
            bf16x8 a = *(const bf16x8*)(&As[(wm+mi*16+lrow)*32 + sw8]);
            #pragma unroll
            for (int ni=0;ni<8;++ni)
                acc[mi][ni] = MFMA(a, b[ni], acc[mi][ni]);
            if constexpr (SPLIT) {
                bf16x8 al = *(const bf16x8*)(&Als[(wm+mi*16+lrow)*32 + sw8]);
                #pragma unroll
                for (int ni=0;ni<8;++ni)
                    acc[mi][ni] = MFMA(al, b[ni], acc[mi][ni]);
            }
        }
        __syncthreads();   // reads done before next iteration's staging overwrites
    }

    #pragma unroll
    for (int ni=0;ni<8;++ni){
        int col = bn + wn + ni*16 + lrow;
        float bv = bias[col];
        #pragma unroll
        for (int mi=0;mi<4;++mi){
            int rowb = bm + wm + mi*16 + quad*4;
            #pragma unroll
            for (int r=0;r<4;++r){
                int row = rowb + r;
                if (row < M) {
                    float v = acc[mi][ni][r] + bv;
                    if constexpr (sizeof(OutT)==4) C[(size_t)row*N + col] = v;
                    else                           C[(size_t)row*N + col] = f2b(v);
                }
            }
        }
    }
}

// ---------------- RoPE in-place on q,k (pure rotation) ----------------
__global__ __launch_bounds__(256)
void rope_kernel(bf16* __restrict__ qkv, const float* __restrict__ rope)
{
    int idx = blockIdx.x*256 + threadIdx.x;
    int d = idx & 31;
    int h = (idx >> 5) & 15;
    int m = idx >> 9;
    if (m >= M_) return;
    int l = m % L_;
    if (l < NREG_) return;
    const float* cp = rope + (size_t)(l - NREG_)*D_;
    const float* sp = rope + (size_t)(L_ - NREG_)*D_ + (size_t)(l - NREG_)*D_;
    float c0 = cp[d], c1 = cp[d+32], s0 = sp[d], s1 = sp[d+32];
    size_t base = (size_t)m*3072 + h*64;
    {
        float a = b2f(qkv[base + d]), b = b2f(qkv[base + d + 32]);
        qkv[base + d]      = f2b(a*c0 - b*s0);
        qkv[base + d + 32] = f2b(b*c1 + a*s1);
    }
    {
        size_t kb = base + 1024;
        float a = b2f(qkv[kb + d]), b = b2f(qkv[kb + d + 32]);
        qkv[kb + d]      = f2b(a*c0 - b*s0);
        qkv[kb + d + 32] = f2b(b*c1 + a*s1);
    }
}

// ---------------- V -> Vt [B*H][D][LP_] (zero-padded cols) ----------------
__global__ __launch_bounds__(256)
void transpose_v(const bf16* __restrict__ qkv, bf16* __restrict__ Vt)
{
    __shared__ bf16 t[64*72];
    int bh = blockIdx.y, lt = blockIdx.x;
    int b = bh >> 4, h = bh & 15;
    int tid = threadIdx.x;
    #pragma unroll
    for (int it=0; it<2; ++it){
        int i = tid + it*256;
        int il = i >> 3, c = (i&7)*8;
        int l = lt*64 + il;
        int4 v = {0,0,0,0};
        if (l < L_) v = *(const int4*)(qkv + ((size_t)b*L_ + l)*3072 + 2048 + h*64 + c);
        *(int4*)(&t[il*72 + c]) = v;
    }
    __syncthreads();
    #pragma unroll
    for (int it=0; it<2; ++it){
        int i = tid + it*256;
        int d = i >> 3, ck = (i&7)*8;
        if (lt*64 + ck + 8 <= LP_){
            union { int4 q; bf16 e[8]; } u;
            #pragma unroll
            for (int j=0;j<8;++j) u.e[j] = t[(ck+j)*72 + d];
            *(int4*)(&Vt[((size_t)bh*64 + d)*LP_ + lt*64 + ck]) = u.q;
        }
    }
}

// ---------------- flash attention (round-6 config: QBLK=192, gl_lds staging) ----------------
// Measured best attn (~122 us, round 6). Register-resident P: PV =
// MFMA(V^T-frag, P-as-B-frag); K slot permutation folded into the gl_lds
// SOURCE address makes each lane's 8 P keys lane-local. QBLK=192 (q_w=48):
// 704 blocks, 40KB LDS -> all blocks co-resident in one dispatch batch
// (QBLK=256's 576 blocks @ 2/CU left a 64-block straggler batch, round 8).
// LDS: Q 192x64 (24KB) + K 64x64 (8KB) + V 64x64 (8KB) = 40KB.
__global__ __launch_bounds__(256,2)
void attn_kernel(const bf16* __restrict__ qkv, const bf16* __restrict__ Vt,
                 float* __restrict__ out)
{
    __shared__ bf16 sQ[192*64];
    __shared__ bf16 sK[64*64];    // [key-slot][d], slot rows permuted via source
    __shared__ bf16 sV[64*64];    // [d][key]

    int tid = threadIdx.x, lane = tid & 63, wave = tid >> 6;
    int lrow = lane & 15, quad = lane >> 4;
    int qt = blockIdx.x, bh = blockIdx.y;
    int b  = bh >> 4, h = bh & 15;
    size_t rowbase = (size_t)b * L_;
    int q0 = qt * 192;

    int l8   = lane >> 3;         // staging sub-row 0..7
    int p3   = lane & 7;          // physical 16B slot (linear dest)
    int swz0 = (quad     ^ (lrow&7))*8;   // read swizzle, slot s=0
    int swz1 = ((4+quad) ^ (lrow&7))*8;   // read swizzle, slot s=1

    // ---- stage Q: 24KB = 24 gl_lds, 6 per wave ----
    #pragma unroll
    for (int it=0; it<6; ++it){
        int ci  = wave*6 + it;
        int row = ci*8 + l8;                 // 0..191
        int ls  = p3 ^ (row&7);
        int gq  = q0 + row; if (gq >= L_) gq = L_-1;
        gl_lds16(qkv + (rowbase + gq)*3072 + h*64 + ls*8, &sQ[ci*512]);
    }
    __syncthreads();

    bf16x8 qf[3][2];
    #pragma unroll
    for (int qi=0;qi<3;++qi){
        qf[qi][0] = *(const bf16x8*)(&sQ[(wave*48 + qi*16 + lrow)*64 + swz0]);
        qf[qi][1] = *(const bf16x8*)(&sQ[(wave*48 + qi*16 + lrow)*64 + swz1]);
    }

    f32x4 o_[3][4] = {};
    f32x4 lsum[3] = {};

    bf16x8 onesf;
    #pragma unroll
    for (int j=0;j<8;++j) onesf[j] = (short)0x3F80;   // bf16 1.0

    const bf16* kgbase = qkv + rowbase*3072 + 1024 + h*64;
    const bf16* vgbase = Vt + (size_t)bh*64*LP_;

    for (int kt = 0; kt <= 32; ++kt) {
        // ---- stage K (8KB) + V (8KB): 2+2 gl_lds per wave ----
        #pragma unroll
        for (int it=0; it<2; ++it){
            int ci  = wave*2 + it;
            int row = ci*8 + l8;                 // slot 0..63
            int ls  = p3 ^ (row&7);
            // slot -> key permutation (lane-local P for PV):
            int key = kt*64 + ((row & 0x23) | ((row & 0x0C) << 1) | ((row & 0x10) >> 2));
            if (key >= L_) key = L_-1;           // tail clamp (masked below)
            gl_lds16(kgbase + (size_t)key*3072 + ls*8, &sK[ci*512]);
        }
        #pragma unroll
        for (int it=0; it<2; ++it){
            int ci  = wave*2 + it;
            int row = ci*8 + l8;                 // d 0..63
            int ls  = p3 ^ (row&7);
            int col = kt*64 + ls*8;
            if (col + 8 > LP_) col = 0;          // tail clamp (P=0 there)
            gl_lds16(vgbase + (size_t)row*LP_ + col, &sV[ci*512]);
        }
        __syncthreads();   // vmcnt(0) drained: staged tile visible

        bool full = (kt != 32);
        int4 pb[3][2];     // P as B-fragments: [qi][32-key half], lane-local

        #pragma unroll
        for (int ki=0; ki<4; ++ki){
            bf16x8 kf0 = *(const bf16x8*)(&sK[(ki*16+lrow)*64 + swz0]);
            bf16x8 kf1 = *(const bf16x8*)(&sK[(ki*16+lrow)*64 + swz1]);
            #pragma unroll
            for (int qi=0; qi<3; ++qi){
                f32x4 t = {};
                t = MFMA(kf0, qf[qi][0], t);
                t = MFMA(kf1, qf[qi][1], t);
                float p[4];
                #pragma unroll
                for (int r=0;r<4;++r){
                    float e = __builtin_amdgcn_exp2f(t[r]*QSC);
                    int keyi = (ki>>1)*32 + quad*8 + (ki&1)*4 + r;
                    p[r] = (full || (2048 + keyi) < L_) ? e : 0.f;
                }
                union { int2 d2; __hip_bfloat162 h2[2]; } u;
                u.h2[0] = __float22bfloat162_rn({p[0], p[1]});
                u.h2[1] = __float22bfloat162_rn({p[2], p[3]});
                if ((ki & 1) == 0){ pb[qi][ki>>1].x = u.d2.x; pb[qi][ki>>1].y = u.d2.y; }
                else              { pb[qi][ki>>1].z = u.d2.x; pb[qi][ki>>1].w = u.d2.y; }
            }
        }

        #pragma unroll
        for (int ni=0; ni<4; ++ni){
            bf16x8 vf0 = *(const bf16x8*)(&sV[(ni*16+lrow)*64 + swz0]);
            bf16x8 vf1 = *(const bf16x8*)(&sV[(ni*16+lrow)*64 + swz1]);
            #pragma unroll
            for (int mi=0; mi<3; ++mi){
                f32x4 t = o_[mi][ni];
                t = MFMA(vf0, as8(pb[mi][0]), t);
                t = MFMA(vf1, as8(pb[mi][1]), t);
                o_[mi][ni] = t;
            }
        }
        #pragma unroll
        for (int mi=0; mi<3; ++mi){
            lsum[mi] = MFMA(onesf, as8(pb[mi][0]), lsum[mi]);
            lsum[mi] = MFMA(onesf, as8(pb[mi][1]), lsum[mi]);
        }
        __syncthreads();   // all reads done before next tile's staging overwrites
    }

    // O^T layout: lane holds q = lane&15 (within mi group), d = ni*16 + quad*4 + r
    #pragma unroll
    for (int mi=0; mi<3; ++mi){
        float inv = 1.f / lsum[mi][0];
        int lq = q0 + wave*48 + mi*16 + lrow;
        if (lq < L_){
            size_t base = (rowbase + lq)*1024 + h*64;
            #pragma unroll
            for (int ni=0; ni<4; ++ni){
                f32x4 t = o_[mi][ni];
                float4 w = {t[0]*inv, t[1]*inv, t[2]*inv, t[3]*inv};
                *(float4*)(&out[base + ni*16 + quad*4]) = w;
            }
        }
    }
}

// ---------------- LayerNorm (fp32 in) -> bf16 ----------------
__global__ __launch_bounds__(256)
void ln_kernel(const float* __restrict__ in, const float* __restrict__ gamma,
               const float* __restrict__ beta, bf16* __restrict__ y)
{
    int row = blockIdx.x;
    int tid = threadIdx.x;
    int wave = tid >> 6, lane = tid & 63;
    float4 v4 = *(const float4*)(in + (size_t)row*1024 + tid*4);
    float v[4] = {v4.x, v4.y, v4.z, v4.w};
    float s = 0.f, q = 0.f;
    #pragma unroll
    for (int j=0;j<4;++j){ s += v[j]; q += v[j]*v[j]; }
    #pragma unroll
    for (int o=1;o<64;o<<=1){ s += __shfl_xor(s, o); q += __shfl_xor(q, o); }
    __shared__ float sh[8];
    if (lane == 0){ sh[wave] = s; sh[4+wave] = q; }
    __syncthreads();
    s = sh[0]+sh[1]+sh[2]+sh[3];
    q = sh[4]+sh[5]+sh[6]+sh[7];
    float mu  = s * (1.f/1024.f);
    float var = q * (1.f/1024.f) - mu*mu;
    float rstd = rsqrtf(var + 1e-5f);
    int2 raw;
    bf16* ob = (bf16*)&raw;
    #pragma unroll
    for (int j=0;j<4;++j){
        float g = gamma[tid*4+j], be = beta[tid*4+j];
        ob[j] = f2b((v[j]-mu)*rstd*g + be);
    }
    *(int2*)(y + (size_t)row*1024 + tid*4) = raw;
}

// ---------------- launch ----------------
extern "C" void kernel_launch(void* const* d_in, const int* in_sizes, int n_in,
                              void* d_out, int out_size, void* d_ws, size_t ws_size,
                              hipStream_t stream)
{
    const float* x     = (const float*)d_in[0];
    const float* rope  = (const float*)d_in[1];
    const float* Wqkv  = (const float*)d_in[2];
    const float* bqkv  = (const float*)d_in[3];
    const float* Wproj = (const float*)d_in[4];
    const float* bproj = (const float*)d_in[5];
    const float* lng   = (const float*)d_in[6];
    const float* lnb   = (const float*)d_in[7];
    float* out = (float*)d_out;

    char* ws = (char*)d_ws;
    size_t off = 0;
    auto alloc = [&](size_t bytes)->char* {
        char* p = ws + off;
        off += (bytes + 255) & ~(size_t)255;
        return p;
    };
    bf16* xhi    = (bf16*)alloc((size_t)M_*C_*2);
    bf16* xlo    = (bf16*)alloc((size_t)M_*C_*2);
    bf16* WqkvT  = (bf16*)alloc((size_t)3*C_*C_*2);
    bf16* WprojT = (bf16*)alloc((size_t)C_*C_*2);
    bf16* qkv    = (bf16*)alloc((size_t)M_*3*C_*2);
    bf16* Vt     = (bf16*)alloc((size_t)B_*H_*D_*LP_*2);

    float* attnF = (float*)xhi;        // xhi+xlo region = exactly M*C*4 bytes
    bf16*  y     = qkv;                // qkv dead after attention

    cvt_split<<<M_*C_/1024, 256, 0, stream>>>(x, xhi, xlo, M_*C_);
    transpose_cvt<<<dim3(3*C_/32, C_/32), dim3(32,8), 0, stream>>>(Wqkv, WqkvT, C_, 3*C_);
    transpose_cvt<<<dim3(C_/32, C_/32), dim3(32,8), 0, stream>>>(Wproj, WprojT, C_, C_);
    gemm_wide<bf16, true><<<(3*C_/256)*((M_+127)/128), 256, 0, stream>>>(
        xhi, xlo, WqkvT, bqkv, qkv, M_, 3*C_, C_, 3*C_/256);
    rope_kernel<<<(M_*H_*32)/256, 256, 0, stream>>>(qkv, rope);
    transpose_v<<<dim3((L_+63)/64, B_*H_), 256, 0, stream>>>(qkv, Vt);
    attn_kernel<<<dim3((L_+191)/192, B_*H_), 256, 0, stream>>>(qkv, Vt, attnF);
    ln_kernel<<<M_, 256, 0, stream>>>(attnF, lng, lnb, y);
    gemm_wide<float, false><<<(C_/256)*((M_+127)/128), 256, 0, stream>>>(
        y, nullptr, WprojT, bproj, out, M_, C_, C_, C_/256);
}

// Round 10
// 411.586 us; speedup vs baseline: 1.0523x; 1.0108x over previous
//
#include <hip/hip_runtime.h>
#include <hip/hip_bf16.h>

#define B_ 4
#define L_ 2052
#define C_ 1024
#define H_ 16
#define D_ 64
#define NREG_ 4
#define M_ (B_*L_)     // 8208
#define LP_ 2056       // padded L stride for Vt (16B-aligned rows)
#define QSC 0.18033688f  // 0.125 * log2(e), applied in fp32 inside attn

typedef short bf16x8 __attribute__((ext_vector_type(8)));
typedef float f32x4 __attribute__((ext_vector_type(4)));
typedef __hip_bfloat16 bf16;

#define MFMA(a,b,c) __builtin_amdgcn_mfma_f32_16x16x32_bf16(a,b,c,0,0,0)

__device__ inline float b2f(bf16 v){ return __bfloat162float(v); }
__device__ inline bf16  f2b(float v){ return __float2bfloat16(v); }
__device__ inline bf16x8 as8(int4 v){ union{int4 i; bf16x8 b;} u; u.i=v; return u.b; }

// async global->LDS, 16B per lane; LDS dest = wave-uniform base + lane*16
__device__ inline void gl_lds16(const void* g, void* l){
    __builtin_amdgcn_global_load_lds(
        (const __attribute__((address_space(1))) void*)g,
        (__attribute__((address_space(3))) void*)l,
        16, 0, 0);
}

// bijective XCD-aware remap (m204): contiguous chunk of ids per XCD
__device__ inline int xcd_swizzle(int orig, int nwg){
    int xcd = orig & 7, idx = orig >> 3;
    int q8 = nwg >> 3, r8 = nwg & 7;
    return (xcd < r8 ? xcd*(q8+1) : r8*(q8+1) + (xcd-r8)*q8) + idx;
}

// ---------------- x -> bf16 hi/lo split ----------------
__global__ __launch_bounds__(256)
void cvt_split(const float* __restrict__ in, bf16* __restrict__ hi,
               bf16* __restrict__ lo, int n)
{
    int i = (blockIdx.x*256 + threadIdx.x)*4;
    if (i >= n) return;
    float4 v = *(const float4*)(in + i);
    int2 hraw, lraw;
    bf16* hp = (bf16*)&hraw;
    bf16* lp = (bf16*)&lraw;
    float vv[4] = {v.x, v.y, v.z, v.w};
    #pragma unroll
    for (int j=0;j<4;++j){
        bf16 h = f2b(vv[j]);
        hp[j] = h;
        lp[j] = f2b(vv[j] - b2f(h));
    }
    *(int2*)(hi + i) = hraw;
    *(int2*)(lo + i) = lraw;
}

// ---------------- fp32 [R][Cc] -> bf16 transposed [Cc][R] ----------------
__global__ __launch_bounds__(256)
void transpose_cvt(const float* __restrict__ in, bf16* __restrict__ out,
                   int R, int Cc)
{
    __shared__ bf16 t[32][33];
    int bx = blockIdx.x * 32;
    int by = blockIdx.y * 32;
    int tx = threadIdx.x;
    int ty = threadIdx.y;
    #pragma unroll
    for (int i=0;i<4;++i){
        int r = by + ty + i*8;
        int c = bx + tx;
        t[ty+i*8][tx] = f2b(in[(size_t)r*Cc + c]);
    }
    __syncthreads();
    #pragma unroll
    for (int i=0;i<4;++i){
        int r = bx + ty + i*8;
        int c = by + tx;
        out[(size_t)r*R + c] = t[tx][ty+i*8];
    }
}

// ---- GEMM, block tile 128x256, wave tile 64x128 (mi4 x ni8) ----
// Round-2 structure + bijective XCD swizzle (T1, VERIFIED round-8: FETCH
// 144.8->69.3 MB, dur 142.4->138.1): 1D grid, chunked id->XCD mapping so
// blocks sharing the A-panel hit the same L2. single-buffer global_load_lds
// width-16, linear LDS (stride 32 = BK), XOR slot swizzle on both sides.
// A[M][K] (+optional lo) x Bt[N][K] -> C[M][N] + bias. N%256==0, K%32==0.
template<typename OutT, bool SPLIT>
__global__ __launch_bounds__(256,2)
void gemm_wide(const bf16* __restrict__ A, const bf16* __restrict__ Alo,
               const bf16* __restrict__ Bt, const float* __restrict__ bias,
               OutT* __restrict__ C, int M, int N, int K, int NBX)
{
    __shared__ bf16 As[128*32];
    __shared__ bf16 Als[SPLIT ? 128*32 : 8];
    __shared__ bf16 Bs[256*32];

    int tid  = threadIdx.x;
    int lane = tid & 63, wave = tid >> 6;
    int wm = (wave>>1)*64, wn = (wave&1)*128;
    int wg = xcd_swizzle(blockIdx.x, gridDim.x);
    int bm = (wg / NBX)*128, bn = (wg % NBX)*256;
    int lrow = lane & 15;
    int quad = lane >> 4;
    int sw8  = (quad ^ ((lrow>>2)&3)) * 8;   // swizzled element offset for frag reads

    f32x4 acc[4][8] = {};

    for (int k0 = 0; k0 < K; k0 += 32) {
        // ---- stage A (+Alo): 8KB each, 2 calls/wave ----
        #pragma unroll
        for (int it=0; it<2; ++it) {
            int o  = (wave*2+it)*1024 + lane*16;  // LDS byte offset this lane lands at
            int r  = o >> 6;                      // row 0..127
            int p  = (o >> 4) & 3;                // physical 16B slot in row
            int ls = p ^ ((r>>2)&3);              // logical slot to fetch
            int ga = bm + r; if (ga >= M) ga = M-1;
            gl_lds16(A + (size_t)ga*K + k0 + ls*8, &As[(wave*2+it)*512]);
            if constexpr (SPLIT)
                gl_lds16(Alo + (size_t)ga*K + k0 + ls*8, &Als[(wave*2+it)*512]);
        }
        // ---- stage B: 16KB, 4 calls/wave ----
        #pragma unroll
        for (int it=0; it<4; ++it) {
            int o  = (wave*4+it)*1024 + lane*16;
            int r  = o >> 6;                      // row 0..255
            int p  = (o >> 4) & 3;
            int ls = p ^ ((r>>2)&3);
            gl_lds16(Bt + (size_t)(bn + r)*K + k0 + ls*8, &Bs[(wave*4+it)*512]);
        }
        __syncthreads();   // compiler drains vmcnt(0) here: staging visible

        bf16x8 b[8];
        #pragma unroll
        for (int i=0;i<8;++i)
            b[i] = *(const bf16x8*)(&Bs[(wn+i*16+lrow)*32 + sw8]);
        #pragma unroll
        for (int mi=0;mi<4;++mi){
            bf16x8 a = *(const bf16x8*)(&As[(wm+mi*16+lrow)*32 + sw8]);
            #pragma unroll
            for (int ni=0;ni<8;++ni)
                acc[mi][ni] = MFMA(a, b[ni], acc[mi][ni]);
            if constexpr (SPLIT) {
                bf16x8 al = *(const bf16x8*)(&Als[(wm+mi*16+lrow)*32 + sw8]);
                #pragma unroll
                for (int ni=0;ni<8;++ni)
                    acc[mi][ni] = MFMA(al, b[ni], acc[mi][ni]);
            }
        }
        __syncthreads();   // reads done before next iteration's staging overwrites
    }

    #pragma unroll
    for (int ni=0;ni<8;++ni){
        int col = bn + wn + ni*16 + lrow;
        float bv = bias[col];
        #pragma unroll
        for (int mi=0;mi<4;++mi){
            int rowb = bm + wm + mi*16 + quad*4;
            #pragma unroll
            for (int r=0;r<4;++r){
                int row = rowb + r;
                if (row < M) {
                    float v = acc[mi][ni][r] + bv;
                    if constexpr (sizeof(OutT)==4) C[(size_t)row*N + col] = v;
                    else                           C[(size_t)row*N + col] = f2b(v);
                }
            }
        }
    }
}

// ---------------- RoPE in-place on q,k (pure rotation) ----------------
__global__ __launch_bounds__(256)
void rope_kernel(bf16* __restrict__ qkv, const float* __restrict__ rope)
{
    int idx = blockIdx.x*256 + threadIdx.x;
    int d = idx & 31;
    int h = (idx >> 5) & 15;
    int m = idx >> 9;
    if (m >= M_) return;
    int l = m % L_;
    if (l < NREG_) return;
    const float* cp = rope + (size_t)(l - NREG_)*D_;
    const float* sp = rope + (size_t)(L_ - NREG_)*D_ + (size_t)(l - NREG_)*D_;
    float c0 = cp[d], c1 = cp[d+32], s0 = sp[d], s1 = sp[d+32];
    size_t base = (size_t)m*3072 + h*64;
    {
        float a = b2f(qkv[base + d]), b = b2f(qkv[base + d + 32]);
        qkv[base + d]      = f2b(a*c0 - b*s0);
        qkv[base + d + 32] = f2b(b*c1 + a*s1);
    }
    {
        size_t kb = base + 1024;
        float a = b2f(qkv[kb + d]), b = b2f(qkv[kb + d + 32]);
        qkv[kb + d]      = f2b(a*c0 - b*s0);
        qkv[kb + d + 32] = f2b(b*c1 + a*s1);
    }
}

// ---------------- V -> Vt [B*H][D][LP_] (zero-padded cols) ----------------
__global__ __launch_bounds__(256)
void transpose_v(const bf16* __restrict__ qkv, bf16* __restrict__ Vt)
{
    __shared__ bf16 t[64*72];
    int bh = blockIdx.y, lt = blockIdx.x;
    int b = bh >> 4, h = bh & 15;
    int tid = threadIdx.x;
    #pragma unroll
    for (int it=0; it<2; ++it){
        int i = tid + it*256;
        int il = i >> 3, c = (i&7)*8;
        int l = lt*64 + il;
        int4 v = {0,0,0,0};
        if (l < L_) v = *(const int4*)(qkv + ((size_t)b*L_ + l)*3072 + 2048 + h*64 + c);
        *(int4*)(&t[il*72 + c]) = v;
    }
    __syncthreads();
    #pragma unroll
    for (int it=0; it<2; ++it){
        int i = tid + it*256;
        int d = i >> 3, ck = (i&7)*8;
        if (lt*64 + ck + 8 <= LP_){
            union { int4 q; bf16 e[8]; } u;
            #pragma unroll
            for (int j=0;j<8;++j) u.e[j] = t[(ck+j)*72 + d];
            *(int4*)(&Vt[((size_t)bh*64 + d)*LP_ + lt*64 + ck]) = u.q;
        }
    }
}

// ---------------- flash attention (round-16: Q-in-reg, 3 blk/CU, XCD swizzle) ----------------
// Round-6 structure (QBLK=192, gl_lds K/V staging, register-resident P) with
// three occupancy/locality levers:
//  (1) sQ LDS stage DELETED: Q fragments loaded directly global->reg once per
//      block (bit-identical values; the staged+swizzled read reproduced plain
//      (row,d) data anyway). LDS 40KB -> 16KB.
//  (2) __launch_bounds__(256,3): 3 blocks/CU -> 704 blocks ALL co-resident,
//      12 waves/CU of TLP to hide the per-tile vmcnt(0) staging drain (the
//      measured 4x gap vs the LDS-pipe bound is exposed load latency).
//  (3) 1D grid + bijective XCD swizzle: bh-major ids -> each XCD's 88 blocks
//      cover 8 bh groups, K/V working set ~4.2MB ~ L2 (GEMM-proven lever).
__global__ __launch_bounds__(256,3)
void attn_kernel(const bf16* __restrict__ qkv, const bf16* __restrict__ Vt,
                 float* __restrict__ out)
{
    __shared__ bf16 sK[64*64];    // [key-slot][d], slot rows permuted via source
    __shared__ bf16 sV[64*64];    // [d][key]

    int tid = threadIdx.x, lane = tid & 63, wave = tid >> 6;
    int lrow = lane & 15, quad = lane >> 4;
    int wg = xcd_swizzle(blockIdx.x, gridDim.x);
    int qt = wg % 11, bh = wg / 11;
    int b  = bh >> 4, h = bh & 15;
    size_t rowbase = (size_t)b * L_;
    int q0 = qt * 192;

    int l8   = lane >> 3;         // staging sub-row 0..7
    int p3   = lane & 7;          // physical 16B slot (linear dest)
    int swz0 = (quad     ^ (lrow&7))*8;   // read swizzle, slot s=0
    int swz1 = ((4+quad) ^ (lrow&7))*8;   // read swizzle, slot s=1

    // ---- Q fragments: direct global->reg (once per block) ----
    bf16x8 qf[3][2];
    #pragma unroll
    for (int qi=0;qi<3;++qi){
        int gq = q0 + wave*48 + qi*16 + lrow;
        if (gq >= L_) gq = L_-1;   // clamped rows compute garbage, never stored
        const bf16* qp = qkv + (rowbase + gq)*3072 + h*64 + quad*8;
        qf[qi][0] = *(const bf16x8*)(qp);
        qf[qi][1] = *(const bf16x8*)(qp + 32);
    }

    f32x4 o_[3][4] = {};
    f32x4 lsum[3] = {};

    bf16x8 onesf;
    #pragma unroll
    for (int j=0;j<8;++j) onesf[j] = (short)0x3F80;   // bf16 1.0

    const bf16* kgbase = qkv + rowbase*3072 + 1024 + h*64;
    const bf16* vgbase = Vt + (size_t)bh*64*LP_;

    for (int kt = 0; kt <= 32; ++kt) {
        // ---- stage K (8KB) + V (8KB): 2+2 gl_lds per wave ----
        #pragma unroll
        for (int it=0; it<2; ++it){
            int ci  = wave*2 + it;
            int row = ci*8 + l8;                 // slot 0..63
            int ls  = p3 ^ (row&7);
            // slot -> key permutation (lane-local P for PV):
            int key = kt*64 + ((row & 0x23) | ((row & 0x0C) << 1) | ((row & 0x10) >> 2));
            if (key >= L_) key = L_-1;           // tail clamp (masked below)
            gl_lds16(kgbase + (size_t)key*3072 + ls*8, &sK[ci*512]);
        }
        #pragma unroll
        for (int it=0; it<2; ++it){
            int ci  = wave*2 + it;
            int row = ci*8 + l8;                 // d 0..63
            int ls  = p3 ^ (row&7);
            int col = kt*64 + ls*8;
            if (col + 8 > LP_) col = 0;          // tail clamp (P=0 there)
            gl_lds16(vgbase + (size_t)row*LP_ + col, &sV[ci*512]);
        }
        __syncthreads();   // vmcnt(0) drained: staged tile visible

        bool full = (kt != 32);
        int4 pb[3][2];     // P as B-fragments: [qi][32-key half], lane-local

        #pragma unroll
        for (int ki=0; ki<4; ++ki){
            bf16x8 kf0 = *(const bf16x8*)(&sK[(ki*16+lrow)*64 + swz0]);
            bf16x8 kf1 = *(const bf16x8*)(&sK[(ki*16+lrow)*64 + swz1]);
            #pragma unroll
            for (int qi=0; qi<3; ++qi){
                f32x4 t = {};
                t = MFMA(kf0, qf[qi][0], t);
                t = MFMA(kf1, qf[qi][1], t);
                float p[4];
                #pragma unroll
                for (int r=0;r<4;++r){
                    float e = __builtin_amdgcn_exp2f(t[r]*QSC);
                    int keyi = (ki>>1)*32 + quad*8 + (ki&1)*4 + r;
                    p[r] = (full || (2048 + keyi) < L_) ? e : 0.f;
                }
                union { int2 d2; __hip_bfloat162 h2[2]; } u;
                u.h2[0] = __float22bfloat162_rn({p[0], p[1]});
                u.h2[1] = __float22bfloat162_rn({p[2], p[3]});
                if ((ki & 1) == 0){ pb[qi][ki>>1].x = u.d2.x; pb[qi][ki>>1].y = u.d2.y; }
                else              { pb[qi][ki>>1].z = u.d2.x; pb[qi][ki>>1].w = u.d2.y; }
            }
        }

        #pragma unroll
        for (int ni=0; ni<4; ++ni){
            bf16x8 vf0 = *(const bf16x8*)(&sV[(ni*16+lrow)*64 + swz0]);
            bf16x8 vf1 = *(const bf16x8*)(&sV[(ni*16+lrow)*64 + swz1]);
            #pragma unroll
            for (int mi=0; mi<3; ++mi){
                f32x4 t = o_[mi][ni];
                t = MFMA(vf0, as8(pb[mi][0]), t);
                t = MFMA(vf1, as8(pb[mi][1]), t);
                o_[mi][ni] = t;
            }
        }
        #pragma unroll
        for (int mi=0; mi<3; ++mi){
            lsum[mi] = MFMA(onesf, as8(pb[mi][0]), lsum[mi]);
            lsum[mi] = MFMA(onesf, as8(pb[mi][1]), lsum[mi]);
        }
        __syncthreads();   // all reads done before next tile's staging overwrites
    }

    // O^T layout: lane holds q = lane&15 (within mi group), d = ni*16 + quad*4 + r
    #pragma unroll
    for (int mi=0; mi<3; ++mi){
        float inv = 1.f / lsum[mi][0];
        int lq = q0 + wave*48 + mi*16 + lrow;
        if (lq < L_){
            size_t base = (rowbase + lq)*1024 + h*64;
            #pragma unroll
            for (int ni=0; ni<4; ++ni){
                f32x4 t = o_[mi][ni];
                float4 w = {t[0]*inv, t[1]*inv, t[2]*inv, t[3]*inv};
                *(float4*)(&out[base + ni*16 + quad*4]) = w;
            }
        }
    }
}

// ---------------- LayerNorm (fp32 in) -> bf16 ----------------
__global__ __launch_bounds__(256)
void ln_kernel(const float* __restrict__ in, const float* __restrict__ gamma,
               const float* __restrict__ beta, bf16* __restrict__ y)
{
    int row = blockIdx.x;
    int tid = threadIdx.x;
    int wave = tid >> 6, lane = tid & 63;
    float4 v4 = *(const float4*)(in + (size_t)row*1024 + tid*4);
    float v[4] = {v4.x, v4.y, v4.z, v4.w};
    float s = 0.f, q = 0.f;
    #pragma unroll
    for (int j=0;j<4;++j){ s += v[j]; q += v[j]*v[j]; }
    #pragma unroll
    for (int o=1;o<64;o<<=1){ s += __shfl_xor(s, o); q += __shfl_xor(q, o); }
    __shared__ float sh[8];
    if (lane == 0){ sh[wave] = s; sh[4+wave] = q; }
    __syncthreads();
    s = sh[0]+sh[1]+sh[2]+sh[3];
    q = sh[4]+sh[5]+sh[6]+sh[7];
    float mu  = s * (1.f/1024.f);
    float var = q * (1.f/1024.f) - mu*mu;
    float rstd = rsqrtf(var + 1e-5f);
    int2 raw;
    bf16* ob = (bf16*)&raw;
    #pragma unroll
    for (int j=0;j<4;++j){
        float g = gamma[tid*4+j], be = beta[tid*4+j];
        ob[j] = f2b((v[j]-mu)*rstd*g + be);
    }
    *(int2*)(y + (size_t)row*1024 + tid*4) = raw;
}

// ---------------- launch ----------------
extern "C" void kernel_launch(void* const* d_in, const int* in_sizes, int n_in,
                              void* d_out, int out_size, void* d_ws, size_t ws_size,
                              hipStream_t stream)
{
    const float* x     = (const float*)d_in[0];
    const float* rope  = (const float*)d_in[1];
    const float* Wqkv  = (const float*)d_in[2];
    const float* bqkv  = (const float*)d_in[3];
    const float* Wproj = (const float*)d_in[4];
    const float* bproj = (const float*)d_in[5];
    const float* lng   = (const float*)d_in[6];
    const float* lnb   = (const float*)d_in[7];
    float* out = (float*)d_out;

    char* ws = (char*)d_ws;
    size_t off = 0;
    auto alloc = [&](size_t bytes)->char* {
        char* p = ws + off;
        off += (bytes + 255) & ~(size_t)255;
        return p;
    };
    bf16* xhi    = (bf16*)alloc((size_t)M_*C_*2);
    bf16* xlo    = (bf16*)alloc((size_t)M_*C_*2);
    bf16* WqkvT  = (bf16*)alloc((size_t)3*C_*C_*2);
    bf16* WprojT = (bf16*)alloc((size_t)C_*C_*2);
    bf16* qkv    = (bf16*)alloc((size_t)M_*3*C_*2);
    bf16* Vt     = (bf16*)alloc((size_t)B_*H_*D_*LP_*2);

    float* attnF = (float*)xhi;        // xhi+xlo region = exactly M*C*4 bytes
    bf16*  y     = qkv;                // qkv dead after attention

    cvt_split<<<M_*C_/1024, 256, 0, stream>>>(x, xhi, xlo, M_*C_);
    transpose_cvt<<<dim3(3*C_/32, C_/32), dim3(32,8), 0, stream>>>(Wqkv, WqkvT, C_, 3*C_);
    transpose_cvt<<<dim3(C_/32, C_/32), dim3(32,8), 0, stream>>>(Wproj, WprojT, C_, C_);
    gemm_wide<bf16, true><<<(3*C_/256)*((M_+127)/128), 256, 0, stream>>>(
        xhi, xlo, WqkvT, bqkv, qkv, M_, 3*C_, C_, 3*C_/256);
    rope_kernel<<<(M_*H_*32)/256, 256, 0, stream>>>(qkv, rope);
    transpose_v<<<dim3((L_+63)/64, B_*H_), 256, 0, stream>>>(qkv, Vt);
    attn_kernel<<<((L_+191)/192)*B_*H_, 256, 0, stream>>>(qkv, Vt, attnF);
    ln_kernel<<<M_, 256, 0, stream>>>(attnF, lng, lnb, y);
    gemm_wide<float, false><<<(C_/256)*((M_+127)/128), 256, 0, stream>>>(
        y, nullptr, WprojT, bproj, out, M_, C_, C_, C_/256);
}

// Round 11
// 384.576 us; speedup vs baseline: 1.1262x; 1.0702x over previous
//
#include <hip/hip_runtime.h>
#include <hip/hip_bf16.h>

#define B_ 4
#define L_ 2052
#define C_ 1024
#define H_ 16
#define D_ 64
#define NREG_ 4
#define M_ (B_*L_)     // 8208
#define LP_ 2056       // padded L stride for Vt (16B-aligned rows)
#define QSC 0.18033688f  // 0.125 * log2(e), applied in fp32 inside attn

typedef short bf16x8 __attribute__((ext_vector_type(8)));
typedef float f32x4 __attribute__((ext_vector_type(4)));
typedef __hip_bfloat16 bf16;

#define MFMA(a,b,c) __builtin_amdgcn_mfma_f32_16x16x32_bf16(a,b,c,0,0,0)

__device__ inline float b2f(bf16 v){ return __bfloat162float(v); }
__device__ inline bf16  f2b(float v){ return __float2bfloat16(v); }
__device__ inline bf16x8 as8(int4 v){ union{int4 i; bf16x8 b;} u; u.i=v; return u.b; }

// async global->LDS, 16B per lane; LDS dest = wave-uniform base + lane*16
__device__ inline void gl_lds16(const void* g, void* l){
    __builtin_amdgcn_global_load_lds(
        (const __attribute__((address_space(1))) void*)g,
        (__attribute__((address_space(3))) void*)l,
        16, 0, 0);
}

// bijective XCD-aware remap (m204): contiguous chunk of ids per XCD
__device__ inline int xcd_swizzle(int orig, int nwg){
    int xcd = orig & 7, idx = orig >> 3;
    int q8 = nwg >> 3, r8 = nwg & 7;
    return (xcd < r8 ? xcd*(q8+1) : r8*(q8+1) + (xcd-r8)*q8) + idx;
}

// ---------------- x -> bf16 hi/lo split ----------------
__global__ __launch_bounds__(256)
void cvt_split(const float* __restrict__ in, bf16* __restrict__ hi,
               bf16* __restrict__ lo, int n)
{
    int i = (blockIdx.x*256 + threadIdx.x)*4;
    if (i >= n) return;
    float4 v = *(const float4*)(in + i);
    int2 hraw, lraw;
    bf16* hp = (bf16*)&hraw;
    bf16* lp = (bf16*)&lraw;
    float vv[4] = {v.x, v.y, v.z, v.w};
    #pragma unroll
    for (int j=0;j<4;++j){
        bf16 h = f2b(vv[j]);
        hp[j] = h;
        lp[j] = f2b(vv[j] - b2f(h));
    }
    *(int2*)(hi + i) = hraw;
    *(int2*)(lo + i) = lraw;
}

// ---------------- fp32 [R][Cc] -> bf16 transposed [Cc][R] ----------------
__global__ __launch_bounds__(256)
void transpose_cvt(const float* __restrict__ in, bf16* __restrict__ out,
                   int R, int Cc)
{
    __shared__ bf16 t[32][33];
    int bx = blockIdx.x * 32;
    int by = blockIdx.y * 32;
    int tx = threadIdx.x;
    int ty = threadIdx.y;
    #pragma unroll
    for (int i=0;i<4;++i){
        int r = by + ty + i*8;
        int c = bx + tx;
        t[ty+i*8][tx] = f2b(in[(size_t)r*Cc + c]);
    }
    __syncthreads();
    #pragma unroll
    for (int i=0;i<4;++i){
        int r = bx + ty + i*8;
        int c = by + tx;
        out[(size_t)r*R + c] = t[tx][ty+i*8];
    }
}

// ---- GEMM, block tile 128x256, wave tile 64x128 (mi4 x ni8) ----
// Round-2 structure + bijective XCD swizzle (VERIFIED: FETCH 144.8->69.3 MB).
// Round-17: ROPE fused into the epilogue (QKV instantiation only). The
// epilogue thread's 8 ni-columns (stride 16) contain both halves (d, d+32)
// of the rotation pairs within one head: pairs (0,2),(1,3),(4,6),(5,7).
// Region q/k/v = (bn+wn)>>10 is wave-uniform. Rotation applied in fp32 on
// the exact accumulator (removes the old double bf16 quantization) before
// the bf16 store; v region passes through. Kills the 67MB rope RMW pass.
// A[M][K] (+optional lo) x Bt[N][K] -> C[M][N] + bias. N%256==0, K%32==0.
template<typename OutT, bool SPLIT, bool ROPE>
__global__ __launch_bounds__(256,2)
void gemm_wide(const bf16* __restrict__ A, const bf16* __restrict__ Alo,
               const bf16* __restrict__ Bt, const float* __restrict__ bias,
               const float* __restrict__ rope_t,
               OutT* __restrict__ C, int M, int N, int K, int NBX)
{
    __shared__ bf16 As[128*32];
    __shared__ bf16 Als[SPLIT ? 128*32 : 8];
    __shared__ bf16 Bs[256*32];

    int tid  = threadIdx.x;
    int lane = tid & 63, wave = tid >> 6;
    int wm = (wave>>1)*64, wn = (wave&1)*128;
    int wg = xcd_swizzle(blockIdx.x, gridDim.x);
    int bm = (wg / NBX)*128, bn = (wg % NBX)*256;
    int lrow = lane & 15;
    int quad = lane >> 4;
    int sw8  = (quad ^ ((lrow>>2)&3)) * 8;   // swizzled element offset for frag reads

    f32x4 acc[4][8] = {};

    for (int k0 = 0; k0 < K; k0 += 32) {
        // ---- stage A (+Alo): 8KB each, 2 calls/wave ----
        #pragma unroll
        for (int it=0; it<2; ++it) {
            int o  = (wave*2+it)*1024 + lane*16;  // LDS byte offset this lane lands at
            int r  = o >> 6;                      // row 0..127
            int p  = (o >> 4) & 3;                // physical 16B slot in row
            int ls = p ^ ((r>>2)&3);              // logical slot to fetch
            int ga = bm + r; if (ga >= M) ga = M-1;
            gl_lds16(A + (size_t)ga*K + k0 + ls*8, &As[(wave*2+it)*512]);
            if constexpr (SPLIT)
                gl_lds16(Alo + (size_t)ga*K + k0 + ls*8, &Als[(wave*2+it)*512]);
        }
        // ---- stage B: 16KB, 4 calls/wave ----
        #pragma unroll
        for (int it=0; it<4; ++it) {
            int o  = (wave*4+it)*1024 + lane*16;
            int r  = o >> 6;                      // row 0..255
            int p  = (o >> 4) & 3;
            int ls = p ^ ((r>>2)&3);
            gl_lds16(Bt + (size_t)(bn + r)*K + k0 + ls*8, &Bs[(wave*4+it)*512]);
        }
        __syncthreads();   // compiler drains vmcnt(0) here: staging visible

        bf16x8 b[8];
        #pragma unroll
        for (int i=0;i<8;++i)
            b[i] = *(const bf16x8*)(&Bs[(wn+i*16+lrow)*32 + sw8]);
        #pragma unroll
        for (int mi=0;mi<4;++mi){
            bf16x8 a = *(const bf16x8*)(&As[(wm+mi*16+lrow)*32 + sw8]);
            #pragma unroll
            for (int ni=0;ni<8;++ni)
                acc[mi][ni] = MFMA(a, b[ni], acc[mi][ni]);
            if constexpr (SPLIT) {
                bf16x8 al = *(const bf16x8*)(&Als[(wm+mi*16+lrow)*32 + sw8]);
                #pragma unroll
                for (int ni=0;ni<8;++ni)
                    acc[mi][ni] = MFMA(al, b[ni], acc[mi][ni]);
            }
        }
        __syncthreads();   // reads done before next iteration's staging overwrites
    }

    float bv[8];
    #pragma unroll
    for (int ni=0;ni<8;++ni) bv[ni] = bias[bn + wn + ni*16 + lrow];

    if constexpr (ROPE) {
        int region = (bn + wn) >> 10;            // 0=q, 1=k, 2=v (wave-uniform)
        #pragma unroll
        for (int mi=0;mi<4;++mi){
            #pragma unroll
            for (int r=0;r<4;++r){
                int row = bm + wm + mi*16 + quad*4 + r;
                if (row >= M) continue;
                int l = row % L_;
                float vv[8];
                #pragma unroll
                for (int ni=0;ni<8;++ni) vv[ni] = acc[mi][ni][r] + bv[ni];
                if (region < 2 && l >= NREG_){
                    const float* cp = rope_t + (size_t)(l - NREG_)*D_;
                    const float* sp = rope_t + (size_t)(L_ - NREG_)*D_ + (size_t)(l - NREG_)*D_;
                    #pragma unroll
                    for (int pi=0; pi<4; ++pi){
                        int n0 = (pi&1) + (pi>>1)*4;   // 0,1,4,5
                        int n1 = n0 + 2;
                        int d  = (pi&1)*16 + lrow;     // 0..31
                        float a = vv[n0], b2 = vv[n1];
                        vv[n0] = a*cp[d]      - b2*sp[d];
                        vv[n1] = b2*cp[d+32]  + a*sp[d+32];
                    }
                }
                #pragma unroll
                for (int ni=0;ni<8;++ni)
                    C[(size_t)row*N + bn + wn + ni*16 + lrow] = f2b(vv[ni]);
            }
        }
    } else {
        #pragma unroll
        for (int ni=0;ni<8;++ni){
            int col = bn + wn + ni*16 + lrow;
            #pragma unroll
            for (int mi=0;mi<4;++mi){
                int rowb = bm + wm + mi*16 + quad*4;
                #pragma unroll
                for (int r=0;r<4;++r){
                    int row = rowb + r;
                    if (row < M) {
                        float v = acc[mi][ni][r] + bv[ni];
                        if constexpr (sizeof(OutT)==4) C[(size_t)row*N + col] = v;
                        else                           C[(size_t)row*N + col] = f2b(v);
                    }
                }
            }
        }
    }
}

// ---------------- V -> Vt [B*H][D][LP_] (zero-padded cols) ----------------
__global__ __launch_bounds__(256)
void transpose_v(const bf16* __restrict__ qkv, bf16* __restrict__ Vt)
{
    __shared__ bf16 t[64*72];
    int bh = blockIdx.y, lt = blockIdx.x;
    int b = bh >> 4, h = bh & 15;
    int tid = threadIdx.x;
    #pragma unroll
    for (int it=0; it<2; ++it){
        int i = tid + it*256;
        int il = i >> 3, c = (i&7)*8;
        int l = lt*64 + il;
        int4 v = {0,0,0,0};
        if (l < L_) v = *(const int4*)(qkv + ((size_t)b*L_ + l)*3072 + 2048 + h*64 + c);
        *(int4*)(&t[il*72 + c]) = v;
    }
    __syncthreads();
    #pragma unroll
    for (int it=0; it<2; ++it){
        int i = tid + it*256;
        int d = i >> 3, ck = (i&7)*8;
        if (lt*64 + ck + 8 <= LP_){
            union { int4 q; bf16 e[8]; } u;
            #pragma unroll
            for (int j=0;j<8;++j) u.e[j] = t[(ck+j)*72 + d];
            *(int4*)(&Vt[((size_t)bh*64 + d)*LP_ + lt*64 + ck]) = u.q;
        }
    }
}

// ---------------- flash attention (round-16 config: Q-in-reg, 3 blk/CU, XCD swizzle) ----------------
// QBLK=192, gl_lds K/V staging, register-resident P. Q fragments loaded
// directly global->reg once per block; LDS 16KB; __launch_bounds__(256,3)
// -> 704 blocks all co-resident; 1D grid + bijective XCD swizzle for K/V L2
// locality. PV = MFMA(V^T-frag, P-as-B-frag); K slot permutation folded into
// the gl_lds SOURCE address makes each lane's 8 P keys lane-local.
__global__ __launch_bounds__(256,3)
void attn_kernel(const bf16* __restrict__ qkv, const bf16* __restrict__ Vt,
                 float* __restrict__ out)
{
    __shared__ bf16 sK[64*64];    // [key-slot][d], slot rows permuted via source
    __shared__ bf16 sV[64*64];    // [d][key]

    int tid = threadIdx.x, lane = tid & 63, wave = tid >> 6;
    int lrow = lane & 15, quad = lane >> 4;
    int wg = xcd_swizzle(blockIdx.x, gridDim.x);
    int qt = wg % 11, bh = wg / 11;
    int b  = bh >> 4, h = bh & 15;
    size_t rowbase = (size_t)b * L_;
    int q0 = qt * 192;

    int l8   = lane >> 3;         // staging sub-row 0..7
    int p3   = lane & 7;          // physical 16B slot (linear dest)
    int swz0 = (quad     ^ (lrow&7))*8;   // read swizzle, slot s=0
    int swz1 = ((4+quad) ^ (lrow&7))*8;   // read swizzle, slot s=1

    // ---- Q fragments: direct global->reg (once per block) ----
    bf16x8 qf[3][2];
    #pragma unroll
    for (int qi=0;qi<3;++qi){
        int gq = q0 + wave*48 + qi*16 + lrow;
        if (gq >= L_) gq = L_-1;   // clamped rows compute garbage, never stored
        const bf16* qp = qkv + (rowbase + gq)*3072 + h*64 + quad*8;
        qf[qi][0] = *(const bf16x8*)(qp);
        qf[qi][1] = *(const bf16x8*)(qp + 32);
    }

    f32x4 o_[3][4] = {};
    f32x4 lsum[3] = {};

    bf16x8 onesf;
    #pragma unroll
    for (int j=0;j<8;++j) onesf[j] = (short)0x3F80;   // bf16 1.0

    const bf16* kgbase = qkv + rowbase*3072 + 1024 + h*64;
    const bf16* vgbase = Vt + (size_t)bh*64*LP_;

    for (int kt = 0; kt <= 32; ++kt) {
        // ---- stage K (8KB) + V (8KB): 2+2 gl_lds per wave ----
        #pragma unroll
        for (int it=0; it<2; ++it){
            int ci  = wave*2 + it;
            int row = ci*8 + l8;                 // slot 0..63
            int ls  = p3 ^ (row&7);
            // slot -> key permutation (lane-local P for PV):
            int key = kt*64 + ((row & 0x23) | ((row & 0x0C) << 1) | ((row & 0x10) >> 2));
            if (key >= L_) key = L_-1;           // tail clamp (masked below)
            gl_lds16(kgbase + (size_t)key*3072 + ls*8, &sK[ci*512]);
        }
        #pragma unroll
        for (int it=0; it<2; ++it){
            int ci  = wave*2 + it;
            int row = ci*8 + l8;                 // d 0..63
            int ls  = p3 ^ (row&7);
            int col = kt*64 + ls*8;
            if (col + 8 > LP_) col = 0;          // tail clamp (P=0 there)
            gl_lds16(vgbase + (size_t)row*LP_ + col, &sV[ci*512]);
        }
        __syncthreads();   // vmcnt(0) drained: staged tile visible

        bool full = (kt != 32);
        int4 pb[3][2];     // P as B-fragments: [qi][32-key half], lane-local

        #pragma unroll
        for (int ki=0; ki<4; ++ki){
            bf16x8 kf0 = *(const bf16x8*)(&sK[(ki*16+lrow)*64 + swz0]);
            bf16x8 kf1 = *(const bf16x8*)(&sK[(ki*16+lrow)*64 + swz1]);
            #pragma unroll
            for (int qi=0; qi<3; ++qi){
                f32x4 t = {};
                t = MFMA(kf0, qf[qi][0], t);
                t = MFMA(kf1, qf[qi][1], t);
                float p[4];
                #pragma unroll
                for (int r=0;r<4;++r){
                    float e = __builtin_amdgcn_exp2f(t[r]*QSC);
                    int keyi = (ki>>1)*32 + quad*8 + (ki&1)*4 + r;
                    p[r] = (full || (2048 + keyi) < L_) ? e : 0.f;
                }
                union { int2 d2; __hip_bfloat162 h2[2]; } u;
                u.h2[0] = __float22bfloat162_rn({p[0], p[1]});
                u.h2[1] = __float22bfloat162_rn({p[2], p[3]});
                if ((ki & 1) == 0){ pb[qi][ki>>1].x = u.d2.x; pb[qi][ki>>1].y = u.d2.y; }
                else              { pb[qi][ki>>1].z = u.d2.x; pb[qi][ki>>1].w = u.d2.y; }
            }
        }

        #pragma unroll
        for (int ni=0; ni<4; ++ni){
            bf16x8 vf0 = *(const bf16x8*)(&sV[(ni*16+lrow)*64 + swz0]);
            bf16x8 vf1 = *(const bf16x8*)(&sV[(ni*16+lrow)*64 + swz1]);
            #pragma unroll
            for (int mi=0; mi<3; ++mi){
                f32x4 t = o_[mi][ni];
                t = MFMA(vf0, as8(pb[mi][0]), t);
                t = MFMA(vf1, as8(pb[mi][1]), t);
                o_[mi][ni] = t;
            }
        }
        #pragma unroll
        for (int mi=0; mi<3; ++mi){
            lsum[mi] = MFMA(onesf, as8(pb[mi][0]), lsum[mi]);
            lsum[mi] = MFMA(onesf, as8(pb[mi][1]), lsum[mi]);
        }
        __syncthreads();   // all reads done before next tile's staging overwrites
    }

    // O^T layout: lane holds q = lane&15 (within mi group), d = ni*16 + quad*4 + r
    #pragma unroll
    for (int mi=0; mi<3; ++mi){
        float inv = 1.f / lsum[mi][0];
        int lq = q0 + wave*48 + mi*16 + lrow;
        if (lq < L_){
            size_t base = (rowbase + lq)*1024 + h*64;
            #pragma unroll
            for (int ni=0; ni<4; ++ni){
                f32x4 t = o_[mi][ni];
                float4 w = {t[0]*inv, t[1]*inv, t[2]*inv, t[3]*inv};
                *(float4*)(&out[base + ni*16 + quad*4]) = w;
            }
        }
    }
}

// ---------------- LayerNorm (fp32 in) -> bf16 ----------------
__global__ __launch_bounds__(256)
void ln_kernel(const float* __restrict__ in, const float* __restrict__ gamma,
               const float* __restrict__ beta, bf16* __restrict__ y)
{
    int row = blockIdx.x;
    int tid = threadIdx.x;
    int wave = tid >> 6, lane = tid & 63;
    float4 v4 = *(const float4*)(in + (size_t)row*1024 + tid*4);
    float v[4] = {v4.x, v4.y, v4.z, v4.w};
    float s = 0.f, q = 0.f;
    #pragma unroll
    for (int j=0;j<4;++j){ s += v[j]; q += v[j]*v[j]; }
    #pragma unroll
    for (int o=1;o<64;o<<=1){ s += __shfl_xor(s, o); q += __shfl_xor(q, o); }
    __shared__ float sh[8];
    if (lane == 0){ sh[wave] = s; sh[4+wave] = q; }
    __syncthreads();
    s = sh[0]+sh[1]+sh[2]+sh[3];
    q = sh[4]+sh[5]+sh[6]+sh[7];
    float mu  = s * (1.f/1024.f);
    float var = q * (1.f/1024.f) - mu*mu;
    float rstd = rsqrtf(var + 1e-5f);
    int2 raw;
    bf16* ob = (bf16*)&raw;
    #pragma unroll
    for (int j=0;j<4;++j){
        float g = gamma[tid*4+j], be = beta[tid*4+j];
        ob[j] = f2b((v[j]-mu)*rstd*g + be);
    }
    *(int2*)(y + (size_t)row*1024 + tid*4) = raw;
}

// ---------------- launch ----------------
extern "C" void kernel_launch(void* const* d_in, const int* in_sizes, int n_in,
                              void* d_out, int out_size, void* d_ws, size_t ws_size,
                              hipStream_t stream)
{
    const float* x     = (const float*)d_in[0];
    const float* rope  = (const float*)d_in[1];
    const float* Wqkv  = (const float*)d_in[2];
    const float* bqkv  = (const float*)d_in[3];
    const float* Wproj = (const float*)d_in[4];
    const float* bproj = (const float*)d_in[5];
    const float* lng   = (const float*)d_in[6];
    const float* lnb   = (const float*)d_in[7];
    float* out = (float*)d_out;

    char* ws = (char*)d_ws;
    size_t off = 0;
    auto alloc = [&](size_t bytes)->char* {
        char* p = ws + off;
        off += (bytes + 255) & ~(size_t)255;
        return p;
    };
    bf16* xhi    = (bf16*)alloc((size_t)M_*C_*2);
    bf16* xlo    = (bf16*)alloc((size_t)M_*C_*2);
    bf16* WqkvT  = (bf16*)alloc((size_t)3*C_*C_*2);
    bf16* WprojT = (bf16*)alloc((size_t)C_*C_*2);
    bf16* qkv    = (bf16*)alloc((size_t)M_*3*C_*2);
    bf16* Vt     = (bf16*)alloc((size_t)B_*H_*D_*LP_*2);

    float* attnF = (float*)xhi;        // xhi+xlo region = exactly M*C*4 bytes
    bf16*  y     = qkv;                // qkv dead after attention

    cvt_split<<<M_*C_/1024, 256, 0, stream>>>(x, xhi, xlo, M_*C_);
    transpose_cvt<<<dim3(3*C_/32, C_/32), dim3(32,8), 0, stream>>>(Wqkv, WqkvT, C_, 3*C_);
    transpose_cvt<<<dim3(C_/32, C_/32), dim3(32,8), 0, stream>>>(Wproj, WprojT, C_, C_);
    gemm_wide<bf16, true, true><<<(3*C_/256)*((M_+127)/128), 256, 0, stream>>>(
        xhi, xlo, WqkvT, bqkv, rope, qkv, M_, 3*C_, C_, 3*C_/256);
    transpose_v<<<dim3((L_+63)/64, B_*H_), 256, 0, stream>>>(qkv, Vt);
    attn_kernel<<<((L_+191)/192)*B_*H_, 256, 0, stream>>>(qkv, Vt, attnF);
    ln_kernel<<<M_, 256, 0, stream>>>(attnF, lng, lnb, y);
    gemm_wide<float, false, false><<<(C_/256)*((M_+127)/128), 256, 0, stream>>>(
        y, nullptr, WprojT, bproj, nullptr, out, M_, C_, C_, C_/256);
}

// Round 12
// 384.444 us; speedup vs baseline: 1.1266x; 1.0003x over previous
//
#include <hip/hip_runtime.h>
#include <hip/hip_bf16.h>

#define B_ 4
#define L_ 2052
#define C_ 1024
#define H_ 16
#define D_ 64
#define NREG_ 4
#define M_ (B_*L_)     // 8208
#define LP_ 2056       // padded L stride for Vt (16B-aligned rows)
#define QSC 0.18033688f  // 0.125 * log2(e), applied in fp32 inside attn

typedef short bf16x8 __attribute__((ext_vector_type(8)));
typedef float f32x4 __attribute__((ext_vector_type(4)));
typedef __hip_bfloat16 bf16;

#define MFMA(a,b,c) __builtin_amdgcn_mfma_f32_16x16x32_bf16(a,b,c,0,0,0)

__device__ inline float b2f(bf16 v){ return __bfloat162float(v); }
__device__ inline bf16  f2b(float v){ return __float2bfloat16(v); }
__device__ inline bf16x8 as8(int4 v){ union{int4 i; bf16x8 b;} u; u.i=v; return u.b; }

// async global->LDS, 16B per lane; LDS dest = wave-uniform base + lane*16
__device__ inline void gl_lds16(const void* g, void* l){
    __builtin_amdgcn_global_load_lds(
        (const __attribute__((address_space(1))) void*)g,
        (__attribute__((address_space(3))) void*)l,
        16, 0, 0);
}

// bijective XCD-aware remap (m204): contiguous chunk of ids per XCD
__device__ inline int xcd_swizzle(int orig, int nwg){
    int xcd = orig & 7, idx = orig >> 3;
    int q8 = nwg >> 3, r8 = nwg & 7;
    return (xcd < r8 ? xcd*(q8+1) : r8*(q8+1) + (xcd-r8)*q8) + idx;
}

// ---------------- x -> bf16 hi/lo split ----------------
__global__ __launch_bounds__(256)
void cvt_split(const float* __restrict__ in, bf16* __restrict__ hi,
               bf16* __restrict__ lo, int n)
{
    int i = (blockIdx.x*256 + threadIdx.x)*4;
    if (i >= n) return;
    float4 v = *(const float4*)(in + i);
    int2 hraw, lraw;
    bf16* hp = (bf16*)&hraw;
    bf16* lp = (bf16*)&lraw;
    float vv[4] = {v.x, v.y, v.z, v.w};
    #pragma unroll
    for (int j=0;j<4;++j){
        bf16 h = f2b(vv[j]);
        hp[j] = h;
        lp[j] = f2b(vv[j] - b2f(h));
    }
    *(int2*)(hi + i) = hraw;
    *(int2*)(lo + i) = lraw;
}

// ---------------- fp32 [R][Cc] -> bf16 transposed [Cc][R] ----------------
__global__ __launch_bounds__(256)
void transpose_cvt(const float* __restrict__ in, bf16* __restrict__ out,
                   int R, int Cc)
{
    __shared__ bf16 t[32][33];
    int bx = blockIdx.x * 32;
    int by = blockIdx.y * 32;
    int tx = threadIdx.x;
    int ty = threadIdx.y;
    #pragma unroll
    for (int i=0;i<4;++i){
        int r = by + ty + i*8;
        int c = bx + tx;
        t[ty+i*8][tx] = f2b(in[(size_t)r*Cc + c]);
    }
    __syncthreads();
    #pragma unroll
    for (int i=0;i<4;++i){
        int r = bx + ty + i*8;
        int c = by + tx;
        out[(size_t)r*R + c] = t[tx][ty+i*8];
    }
}

// ---- GEMM, block tile 128x256, wave tile 64x128 (mi4 x ni8) ----
// Round-18: T4 counted-vmcnt pipeline on the proven structure. Double-buffered
// LDS; per K-step: issue next tile's global_load_lds FIRST, then
// s_waitcnt vmcnt(8|6) (waits ONLY for the current tile's loads — the
// prefetch stays in flight across the barrier, never drained to 0 in the
// main loop), raw s_barrier (no compiler drain), compute, raw s_barrier
// (guards buffer reuse). Last iter drains vmcnt(0). XCD swizzle + XOR slot
// swizzle + ROPE-fused epilogue unchanged (all measured wins).
// A[M][K] (+optional lo) x Bt[N][K] -> C[M][N] + bias. N%256==0, K%32==0.
template<typename OutT, bool SPLIT, bool ROPE>
__global__ __launch_bounds__(256,2)
void gemm_wide(const bf16* __restrict__ A, const bf16* __restrict__ Alo,
               const bf16* __restrict__ Bt, const float* __restrict__ bias,
               const float* __restrict__ rope_t,
               OutT* __restrict__ C, int M, int N, int K, int NBX)
{
    __shared__ bf16 As[2][128*32];
    __shared__ bf16 Als[SPLIT ? 2*128*32 : 8];
    __shared__ bf16 Bs[2][256*32];

    int tid  = threadIdx.x;
    int lane = tid & 63, wave = tid >> 6;
    int wm = (wave>>1)*64, wn = (wave&1)*128;
    int wg = xcd_swizzle(blockIdx.x, gridDim.x);
    int bm = (wg / NBX)*128, bn = (wg % NBX)*256;
    int lrow = lane & 15;
    int quad = lane >> 4;
    int sw8  = (quad ^ ((lrow>>2)&3)) * 8;   // swizzled element offset for frag reads

    f32x4 acc[4][8] = {};

    auto STAGE = [&](int buf, int k0){
        #pragma unroll
        for (int it=0; it<2; ++it) {
            int o  = (wave*2+it)*1024 + lane*16;  // LDS byte offset this lane lands at
            int r  = o >> 6;                      // row 0..127
            int p  = (o >> 4) & 3;                // physical 16B slot in row
            int ls = p ^ ((r>>2)&3);              // logical slot to fetch
            int ga = bm + r; if (ga >= M) ga = M-1;
            gl_lds16(A + (size_t)ga*K + k0 + ls*8, &As[buf][(wave*2+it)*512]);
            if constexpr (SPLIT)
                gl_lds16(Alo + (size_t)ga*K + k0 + ls*8, &Als[buf*4096 + (wave*2+it)*512]);
        }
        #pragma unroll
        for (int it=0; it<4; ++it) {
            int o  = (wave*4+it)*1024 + lane*16;
            int r  = o >> 6;                      // row 0..255
            int p  = (o >> 4) & 3;
            int ls = p ^ ((r>>2)&3);
            gl_lds16(Bt + (size_t)(bn + r)*K + k0 + ls*8, &Bs[buf][(wave*4+it)*512]);
        }
    };

    int nt = K >> 5;
    int cur = 0;
    STAGE(0, 0);                       // prologue: tile 0 in flight

    for (int t = 0; t < nt; ++t) {
        if (t+1 < nt) {
            STAGE(cur^1, (t+1)*32);    // issue next tile (8|6 more loads in flight)
            // wait ONLY for tile t's loads; prefetch stays outstanding:
            if constexpr (SPLIT) asm volatile("s_waitcnt vmcnt(8)" ::: "memory");
            else                 asm volatile("s_waitcnt vmcnt(6)" ::: "memory");
        } else {
            asm volatile("s_waitcnt vmcnt(0)" ::: "memory");   // final drain
        }
        __builtin_amdgcn_s_barrier();  // all waves: buf[cur] fully staged

        bf16x8 b[8];
        #pragma unroll
        for (int i=0;i<8;++i)
            b[i] = *(const bf16x8*)(&Bs[cur][(wn+i*16+lrow)*32 + sw8]);
        #pragma unroll
        for (int mi=0;mi<4;++mi){
            bf16x8 a = *(const bf16x8*)(&As[cur][(wm+mi*16+lrow)*32 + sw8]);
            #pragma unroll
            for (int ni=0;ni<8;++ni)
                acc[mi][ni] = MFMA(a, b[ni], acc[mi][ni]);
            if constexpr (SPLIT) {
                bf16x8 al = *(const bf16x8*)(&Als[cur*4096 + (wm+mi*16+lrow)*32 + sw8]);
                #pragma unroll
                for (int ni=0;ni<8;++ni)
                    acc[mi][ni] = MFMA(al, b[ni], acc[mi][ni]);
            }
        }
        __builtin_amdgcn_s_barrier();  // all waves done reading buf[cur]
        cur ^= 1;                      // next iter stages into the just-read buf
    }

    float bv[8];
    #pragma unroll
    for (int ni=0;ni<8;++ni) bv[ni] = bias[bn + wn + ni*16 + lrow];

    if constexpr (ROPE) {
        int region = (bn + wn) >> 10;            // 0=q, 1=k, 2=v (wave-uniform)
        #pragma unroll
        for (int mi=0;mi<4;++mi){
            #pragma unroll
            for (int r=0;r<4;++r){
                int row = bm + wm + mi*16 + quad*4 + r;
                if (row >= M) continue;
                int l = row % L_;
                float vv[8];
                #pragma unroll
                for (int ni=0;ni<8;++ni) vv[ni] = acc[mi][ni][r] + bv[ni];
                if (region < 2 && l >= NREG_){
                    const float* cp = rope_t + (size_t)(l - NREG_)*D_;
                    const float* sp = rope_t + (size_t)(L_ - NREG_)*D_ + (size_t)(l - NREG_)*D_;
                    #pragma unroll
                    for (int pi=0; pi<4; ++pi){
                        int n0 = (pi&1) + (pi>>1)*4;   // 0,1,4,5
                        int n1 = n0 + 2;
                        int d  = (pi&1)*16 + lrow;     // 0..31
                        float a = vv[n0], b2 = vv[n1];
                        vv[n0] = a*cp[d]      - b2*sp[d];
                        vv[n1] = b2*cp[d+32]  + a*sp[d+32];
                    }
                }
                #pragma unroll
                for (int ni=0;ni<8;++ni)
                    C[(size_t)row*N + bn + wn + ni*16 + lrow] = f2b(vv[ni]);
            }
        }
    } else {
        #pragma unroll
        for (int ni=0;ni<8;++ni){
            int col = bn + wn + ni*16 + lrow;
            #pragma unroll
            for (int mi=0;mi<4;++mi){
                int rowb = bm + wm + mi*16 + quad*4;
                #pragma unroll
                for (int r=0;r<4;++r){
                    int row = rowb + r;
                    if (row < M) {
                        float v = acc[mi][ni][r] + bv[ni];
                        if constexpr (sizeof(OutT)==4) C[(size_t)row*N + col] = v;
                        else                           C[(size_t)row*N + col] = f2b(v);
                    }
                }
            }
        }
    }
}

// ---------------- V -> Vt [B*H][D][LP_] (zero-padded cols) ----------------
__global__ __launch_bounds__(256)
void transpose_v(const bf16* __restrict__ qkv, bf16* __restrict__ Vt)
{
    __shared__ bf16 t[64*72];
    int bh = blockIdx.y, lt = blockIdx.x;
    int b = bh >> 4, h = bh & 15;
    int tid = threadIdx.x;
    #pragma unroll
    for (int it=0; it<2; ++it){
        int i = tid + it*256;
        int il = i >> 3, c = (i&7)*8;
        int l = lt*64 + il;
        int4 v = {0,0,0,0};
        if (l < L_) v = *(const int4*)(qkv + ((size_t)b*L_ + l)*3072 + 2048 + h*64 + c);
        *(int4*)(&t[il*72 + c]) = v;
    }
    __syncthreads();
    #pragma unroll
    for (int it=0; it<2; ++it){
        int i = tid + it*256;
        int d = i >> 3, ck = (i&7)*8;
        if (lt*64 + ck + 8 <= LP_){
            union { int4 q; bf16 e[8]; } u;
            #pragma unroll
            for (int j=0;j<8;++j) u.e[j] = t[(ck+j)*72 + d];
            *(int4*)(&Vt[((size_t)bh*64 + d)*LP_ + lt*64 + ck]) = u.q;
        }
    }
}

// ---------------- flash attention (round-16 config: Q-in-reg, 3 blk/CU, XCD swizzle) ----------------
// QBLK=192, gl_lds K/V staging, register-resident P. Q fragments loaded
// directly global->reg once per block; LDS 16KB; __launch_bounds__(256,3)
// -> 704 blocks all co-resident; 1D grid + bijective XCD swizzle for K/V L2
// locality. PV = MFMA(V^T-frag, P-as-B-frag); K slot permutation folded into
// the gl_lds SOURCE address makes each lane's 8 P keys lane-local.
__global__ __launch_bounds__(256,3)
void attn_kernel(const bf16* __restrict__ qkv, const bf16* __restrict__ Vt,
                 float* __restrict__ out)
{
    __shared__ bf16 sK[64*64];    // [key-slot][d], slot rows permuted via source
    __shared__ bf16 sV[64*64];    // [d][key]

    int tid = threadIdx.x, lane = tid & 63, wave = tid >> 6;
    int lrow = lane & 15, quad = lane >> 4;
    int wg = xcd_swizzle(blockIdx.x, gridDim.x);
    int qt = wg % 11, bh = wg / 11;
    int b  = bh >> 4, h = bh & 15;
    size_t rowbase = (size_t)b * L_;
    int q0 = qt * 192;

    int l8   = lane >> 3;         // staging sub-row 0..7
    int p3   = lane & 7;          // physical 16B slot (linear dest)
    int swz0 = (quad     ^ (lrow&7))*8;   // read swizzle, slot s=0
    int swz1 = ((4+quad) ^ (lrow&7))*8;   // read swizzle, slot s=1

    // ---- Q fragments: direct global->reg (once per block) ----
    bf16x8 qf[3][2];
    #pragma unroll
    for (int qi=0;qi<3;++qi){
        int gq = q0 + wave*48 + qi*16 + lrow;
        if (gq >= L_) gq = L_-1;   // clamped rows compute garbage, never stored
        const bf16* qp = qkv + (rowbase + gq)*3072 + h*64 + quad*8;
        qf[qi][0] = *(const bf16x8*)(qp);
        qf[qi][1] = *(const bf16x8*)(qp + 32);
    }

    f32x4 o_[3][4] = {};
    f32x4 lsum[3] = {};

    bf16x8 onesf;
    #pragma unroll
    for (int j=0;j<8;++j) onesf[j] = (short)0x3F80;   // bf16 1.0

    const bf16* kgbase = qkv + rowbase*3072 + 1024 + h*64;
    const bf16* vgbase = Vt + (size_t)bh*64*LP_;

    for (int kt = 0; kt <= 32; ++kt) {
        // ---- stage K (8KB) + V (8KB): 2+2 gl_lds per wave ----
        #pragma unroll
        for (int it=0; it<2; ++it){
            int ci  = wave*2 + it;
            int row = ci*8 + l8;                 // slot 0..63
            int ls  = p3 ^ (row&7);
            // slot -> key permutation (lane-local P for PV):
            int key = kt*64 + ((row & 0x23) | ((row & 0x0C) << 1) | ((row & 0x10) >> 2));
            if (key >= L_) key = L_-1;           // tail clamp (masked below)
            gl_lds16(kgbase + (size_t)key*3072 + ls*8, &sK[ci*512]);
        }
        #pragma unroll
        for (int it=0; it<2; ++it){
            int ci  = wave*2 + it;
            int row = ci*8 + l8;                 // d 0..63
            int ls  = p3 ^ (row&7);
            int col = kt*64 + ls*8;
            if (col + 8 > LP_) col = 0;          // tail clamp (P=0 there)
            gl_lds16(vgbase + (size_t)row*LP_ + col, &sV[ci*512]);
        }
        __syncthreads();   // vmcnt(0) drained: staged tile visible

        bool full = (kt != 32);
        int4 pb[3][2];     // P as B-fragments: [qi][32-key half], lane-local

        #pragma unroll
        for (int ki=0; ki<4; ++ki){
            bf16x8 kf0 = *(const bf16x8*)(&sK[(ki*16+lrow)*64 + swz0]);
            bf16x8 kf1 = *(const bf16x8*)(&sK[(ki*16+lrow)*64 + swz1]);
            #pragma unroll
            for (int qi=0; qi<3; ++qi){
                f32x4 t = {};
                t = MFMA(kf0, qf[qi][0], t);
                t = MFMA(kf1, qf[qi][1], t);
                float p[4];
                #pragma unroll
                for (int r=0;r<4;++r){
                    float e = __builtin_amdgcn_exp2f(t[r]*QSC);
                    int keyi = (ki>>1)*32 + quad*8 + (ki&1)*4 + r;
                    p[r] = (full || (2048 + keyi) < L_) ? e : 0.f;
                }
                union { int2 d2; __hip_bfloat162 h2[2]; } u;
                u.h2[0] = __float22bfloat162_rn({p[0], p[1]});
                u.h2[1] = __float22bfloat162_rn({p[2], p[3]});
                if ((ki & 1) == 0){ pb[qi][ki>>1].x = u.d2.x; pb[qi][ki>>1].y = u.d2.y; }
                else              { pb[qi][ki>>1].z = u.d2.x; pb[qi][ki>>1].w = u.d2.y; }
            }
        }

        #pragma unroll
        for (int ni=0; ni<4; ++ni){
            bf16x8 vf0 = *(const bf16x8*)(&sV[(ni*16+lrow)*64 + swz0]);
            bf16x8 vf1 = *(const bf16x8*)(&sV[(ni*16+lrow)*64 + swz1]);
            #pragma unroll
            for (int mi=0; mi<3; ++mi){
                f32x4 t = o_[mi][ni];
                t = MFMA(vf0, as8(pb[mi][0]), t);
                t = MFMA(vf1, as8(pb[mi][1]), t);
                o_[mi][ni] = t;
            }
        }
        #pragma unroll
        for (int mi=0; mi<3; ++mi){
            lsum[mi] = MFMA(onesf, as8(pb[mi][0]), lsum[mi]);
            lsum[mi] = MFMA(onesf, as8(pb[mi][1]), lsum[mi]);
        }
        __syncthreads();   // all reads done before next tile's staging overwrites
    }

    // O^T layout: lane holds q = lane&15 (within mi group), d = ni*16 + quad*4 + r
    #pragma unroll
    for (int mi=0; mi<3; ++mi){
        float inv = 1.f / lsum[mi][0];
        int lq = q0 + wave*48 + mi*16 + lrow;
        if (lq < L_){
            size_t base = (rowbase + lq)*1024 + h*64;
            #pragma unroll
            for (int ni=0; ni<4; ++ni){
                f32x4 t = o_[mi][ni];
                float4 w = {t[0]*inv, t[1]*inv, t[2]*inv, t[3]*inv};
                *(float4*)(&out[base + ni*16 + quad*4]) = w;
            }
        }
    }
}

// ---------------- LayerNorm (fp32 in) -> bf16 ----------------
__global__ __launch_bounds__(256)
void ln_kernel(const float* __restrict__ in, const float* __restrict__ gamma,
               const float* __restrict__ beta, bf16* __restrict__ y)
{
    int row = blockIdx.x;
    int tid = threadIdx.x;
    int wave = tid >> 6, lane = tid & 63;
    float4 v4 = *(const float4*)(in + (size_t)row*1024 + tid*4);
    float v[4] = {v4.x, v4.y, v4.z, v4.w};
    float s = 0.f, q = 0.f;
    #pragma unroll
    for (int j=0;j<4;++j){ s += v[j]; q += v[j]*v[j]; }
    #pragma unroll
    for (int o=1;o<64;o<<=1){ s += __shfl_xor(s, o); q += __shfl_xor(q, o); }
    __shared__ float sh[8];
    if (lane == 0){ sh[wave] = s; sh[4+wave] = q; }
    __syncthreads();
    s = sh[0]+sh[1]+sh[2]+sh[3];
    q = sh[4]+sh[5]+sh[6]+sh[7];
    float mu  = s * (1.f/1024.f);
    float var = q * (1.f/1024.f) - mu*mu;
    float rstd = rsqrtf(var + 1e-5f);
    int2 raw;
    bf16* ob = (bf16*)&raw;
    #pragma unroll
    for (int j=0;j<4;++j){
        float g = gamma[tid*4+j], be = beta[tid*4+j];
        ob[j] = f2b((v[j]-mu)*rstd*g + be);
    }
    *(int2*)(y + (size_t)row*1024 + tid*4) = raw;
}

// ---------------- launch ----------------
extern "C" void kernel_launch(void* const* d_in, const int* in_sizes, int n_in,
                              void* d_out, int out_size, void* d_ws, size_t ws_size,
                              hipStream_t stream)
{
    const float* x     = (const float*)d_in[0];
    const float* rope  = (const float*)d_in[1];
    const float* Wqkv  = (const float*)d_in[2];
    const float* bqkv  = (const float*)d_in[3];
    const float* Wproj = (const float*)d_in[4];
    const float* bproj = (const float*)d_in[5];
    const float* lng   = (const float*)d_in[6];
    const float* lnb   = (const float*)d_in[7];
    float* out = (float*)d_out;

    char* ws = (char*)d_ws;
    size_t off = 0;
    auto alloc = [&](size_t bytes)->char* {
        char* p = ws + off;
        off += (bytes + 255) & ~(size_t)255;
        return p;
    };
    bf16* xhi    = (bf16*)alloc((size_t)M_*C_*2);
    bf16* xlo    = (bf16*)alloc((size_t)M_*C_*2);
    bf16* WqkvT  = (bf16*)alloc((size_t)3*C_*C_*2);
    bf16* WprojT = (bf16*)alloc((size_t)C_*C_*2);
    bf16* qkv    = (bf16*)alloc((size_t)M_*3*C_*2);
    bf16* Vt     = (bf16*)alloc((size_t)B_*H_*D_*LP_*2);

    float* attnF = (float*)xhi;        // xhi+xlo region = exactly M*C*4 bytes
    bf16*  y     = qkv;                // qkv dead after attention

    cvt_split<<<M_*C_/1024, 256, 0, stream>>>(x, xhi, xlo, M_*C_);
    transpose_cvt<<<dim3(3*C_/32, C_/32), dim3(32,8), 0, stream>>>(Wqkv, WqkvT, C_, 3*C_);
    transpose_cvt<<<dim3(C_/32, C_/32), dim3(32,8), 0, stream>>>(Wproj, WprojT, C_, C_);
    gemm_wide<bf16, true, true><<<(3*C_/256)*((M_+127)/128), 256, 0, stream>>>(
        xhi, xlo, WqkvT, bqkv, rope, qkv, M_, 3*C_, C_, 3*C_/256);
    transpose_v<<<dim3((L_+63)/64, B_*H_), 256, 0, stream>>>(qkv, Vt);
    attn_kernel<<<((L_+191)/192)*B_*H_, 256, 0, stream>>>(qkv, Vt, attnF);
    ln_kernel<<<M_, 256, 0, stream>>>(attnF, lng, lnb, y);
    gemm_wide<float, false, false><<<(C_/256)*((M_+127)/128), 256, 0, stream>>>(
        y, nullptr, WprojT, bproj, nullptr, out, M_, C_, C_, C_/256);
}